// Round 9
// baseline (232.382 us; speedup 1.0000x reference)
//
#include <hip/hip_runtime.h>
#include <stdint.h>

#define D_IN   4096
#define D_OUT  4096
#define NTOK   4096
#define NW     (D_OUT * D_IN)          // 16777216
#define RANK1  15099493u               // floor(0.9f * (NW-1)) as jax computes in f32
#define CAP    1500000                 // candidate list capacity (expected ~700K)

typedef unsigned int  uint32;
typedef unsigned short ushort_t;
typedef float  f32x4  __attribute__((ext_vector_type(4)));
typedef __bf16 bf16x8 __attribute__((ext_vector_type(8)));

// ---------- helpers ----------
__device__ __forceinline__ uint32 rne_bf16(float f) {
  uint32 u = __float_as_uint(f);
  return (u + 0x7FFFu + ((u >> 16) & 1u)) >> 16;
}

__device__ __forceinline__ void gload_lds16(const void* g, void* l) {
  __builtin_amdgcn_global_load_lds((__attribute__((address_space(1))) void*)(g),
                                   (__attribute__((address_space(3))) void*)(l), 16, 0, 0);
}

// block-redundant select: find bin containing `rank` in NB-bin global histogram.
template <int NB>
__device__ __forceinline__ void dsel(const uint32* __restrict__ h, uint32 rank,
                                     uint32* res, uint32* wtot) {
  constexpr int PER = NB >> 8;
  int tid = threadIdx.x;
  int lane = tid & 63, wid = tid >> 6;
  uint32 loc[PER];
  uint32 s = 0;
  int base = tid * PER;
#pragma unroll
  for (int i = 0; i < PER; i++) { loc[i] = h[base + i]; s += loc[i]; }
  uint32 v = s;
  for (int d = 1; d < 64; d <<= 1) { uint32 o = __shfl_up(v, (unsigned)d); if (lane >= d) v += o; }
  if (lane == 63) wtot[wid] = v;
  __syncthreads();
  uint32 woff = 0;
  for (int w = 0; w < wid; w++) woff += wtot[w];
  uint32 incl = v + woff, excl = incl - s;
  if (rank >= excl && rank < incl) {
    uint32 c = excl;
#pragma unroll
    for (int i = 0; i < PER; i++) {
      if (rank < c + loc[i]) { res[0] = (uint32)(base + i); res[1] = rank - c; break; }
      c += loc[i];
    }
  }
  __syncthreads();
}

// ---------- K1: hist pass 1 (blocks 0..2047) + convert_x (blocks 2048..5119) ----------
__global__ void k1_hist1_convx(const uint4* __restrict__ wb, uint32* __restrict__ hist,
                               const float4* __restrict__ x, uint4* __restrict__ xout) {
  __shared__ uint32 lh[4][2048];
  if (blockIdx.x < 2048) {
    for (int i = threadIdx.x; i < 8192; i += 256) ((uint32*)lh)[i] = 0;
    __syncthreads();
    int wid = threadIdx.x >> 6;
    int idx = blockIdx.x * 256 + threadIdx.x;
    for (int i = idx; i < NW / 4; i += 2048 * 256) {
      uint4 v = wb[i];
      atomicAdd(&lh[wid][(v.x & 0x7FFFFFFFu) >> 20], 1u);
      atomicAdd(&lh[wid][(v.y & 0x7FFFFFFFu) >> 20], 1u);
      atomicAdd(&lh[wid][(v.z & 0x7FFFFFFFu) >> 20], 1u);
      atomicAdd(&lh[wid][(v.w & 0x7FFFFFFFu) >> 20], 1u);
    }
    __syncthreads();
    for (int i = threadIdx.x; i < 2048; i += 256) {
      uint32 c = lh[0][i] + lh[1][i] + lh[2][i] + lh[3][i];
      if (c) atomicAdd(&hist[i], c);
    }
  } else {
    int i = (blockIdx.x - 2048) * 256 + threadIdx.x;
    for (; i < NW / 8; i += 3072 * 256) {
      float4 a = x[2 * i], b = x[2 * i + 1];
      uint4 o;
      o.x = rne_bf16(a.x) | (rne_bf16(a.y) << 16);
      o.y = rne_bf16(a.z) | (rne_bf16(a.w) << 16);
      o.z = rne_bf16(b.x) | (rne_bf16(b.y) << 16);
      o.w = rne_bf16(b.z) | (rne_bf16(b.w) << 16);
      xout[i] = o;
    }
  }
}

// ---------- K2: decide + convert W + compact candidates + FUSED s1 hist ----------
__global__ void k2_decide(const float4* __restrict__ w, const uint32* __restrict__ hist1,
                          uint4* __restrict__ out, uint2* __restrict__ cand,
                          uint32* __restrict__ cnt, uint32* __restrict__ hs1) {
  __shared__ uint32 res1[2], wt[4];
  __shared__ uint32 lcnt, lbase;
  __shared__ uint2 lbuf[3072];
  __shared__ uint32 lch[1024];
  for (int i = threadIdx.x; i < 1024; i += 256) lch[i] = 0;
  if (threadIdx.x == 0) lcnt = 0;
  dsel<2048>(hist1, RANK1, res1, wt);          // internal syncthreads orders the zeroing
  uint32 bstar = res1[0];
  int i = blockIdx.x * 256 + threadIdx.x;
  for (; i < NW / 8; i += 2048 * 256) {
    float4 a = w[2 * i], b = w[2 * i + 1];
    float f[8] = {a.x, a.y, a.z, a.w, b.x, b.y, b.z, b.w};
    uint32 h[8];
#pragma unroll
    for (int j = 0; j < 8; j++) {
      uint32 bits = __float_as_uint(f[j]);
      uint32 bin = (bits & 0x7FFFFFFFu) >> 20;
      h[j] = (bin > bstar) ? rne_bf16(f[j]) : 0u;
      if (bin == bstar) {
        uint32 p = atomicAdd(&lcnt, 1u);
        if (p < 3072) {
          lbuf[p] = make_uint2((uint32)(8 * i + j), bits);
          atomicAdd(&lch[(bits >> 10) & 1023u], 1u);
        }
      }
    }
    uint4 o;
    o.x = h[0] | (h[1] << 16);
    o.y = h[2] | (h[3] << 16);
    o.z = h[4] | (h[5] << 16);
    o.w = h[6] | (h[7] << 16);
    out[i] = o;
  }
  __syncthreads();
  uint32 nstore = lcnt < 3072u ? lcnt : 3072u;
  if (threadIdx.x == 0) lbase = atomicAdd(cnt, nstore);
  __syncthreads();
  for (uint32 p = threadIdx.x; p < nstore; p += 256) {
    uint32 g = lbase + p;
    if (g < CAP) cand[g] = lbuf[p];
  }
  for (int ii = threadIdx.x; ii < 1024; ii += 256) if (lch[ii]) atomicAdd(&hs1[ii], lch[ii]);
}

// ---------- S2: filter on bits[19:10], hist bits [9:0] ----------
__global__ void s2_hist(const uint2* __restrict__ cand, const uint32* __restrict__ cnt,
                        const uint32* __restrict__ hist1, const uint32* __restrict__ hs1,
                        uint32* __restrict__ hs2) {
  __shared__ uint32 lh[1024];
  __shared__ uint32 res1[2], res2[2], wt[4];
  for (int i = threadIdx.x; i < 1024; i += 256) lh[i] = 0;
  dsel<2048>(hist1, RANK1, res1, wt);
  dsel<1024>(hs1, res1[1], res2, wt);
  uint32 b2 = res2[0];
  uint32 n = *cnt; if (n > CAP) n = CAP;
  for (uint32 i = blockIdx.x * 256 + threadIdx.x; i < n; i += gridDim.x * 256) {
    uint32 mag = cand[i].y & 0x7FFFFFFFu;
    if (((mag >> 10) & 1023u) == b2) atomicAdd(&lh[mag & 1023u], 1u);
  }
  __syncthreads();
  for (int i = threadIdx.x; i < 1024; i += 256) if (lh[i]) atomicAdd(&hs2[i], lh[i]);
}

// ---------- K5: final threshold, fix up kept candidates ----------
__global__ void k5_fixup(const uint2* __restrict__ cand, const uint32* __restrict__ cnt,
                         const uint32* __restrict__ hist1, const uint32* __restrict__ hs1,
                         const uint32* __restrict__ hs2, ushort_t* __restrict__ wb) {
  __shared__ uint32 res1[2], res2[2], res3[2], wt[4];
  dsel<2048>(hist1, RANK1, res1, wt);
  dsel<1024>(hs1, res1[1], res2, wt);
  dsel<1024>(hs2, res2[1], res3, wt);
  uint32 thr_mag = (res1[0] << 20) | (res2[0] << 10) | res3[0];
  uint32 n = *cnt; if (n > CAP) n = CAP;
  for (uint32 i = blockIdx.x * 256 + threadIdx.x; i < n; i += gridDim.x * 256) {
    uint2 c = cand[i];
    uint32 mag = c.y & 0x7FFFFFFFu;
    if (mag > thr_mag) wb[c.x] = (ushort_t)rne_bf16(__uint_as_float(c.y));
  }
}

// ---------- GEMM: C[M,N] = Xb[M,K] * Wb[N,K]^T + bias ----------
// PROVEN R5 structure (103.5 us, MfmaUtil 58.7%): 256x256 tile, BK=32, 8 waves
// (2x4), QUAD-buffered LDS (128KB), stage 3-ahead, software-pipelined frag
// reads; each MFMA burst runs with 4-8 ds_reads in flight for the NEXT
// half-tile. One barrier + one counted vmcnt(4) per K-tile (never 0).
#define TILES 128

#define MF16(AF, BF, MO)                                                                          \
  acc[(MO)+0][0] = __builtin_amdgcn_mfma_f32_16x16x32_bf16(AF[0], BF[0], acc[(MO)+0][0], 0,0,0);  \
  acc[(MO)+0][1] = __builtin_amdgcn_mfma_f32_16x16x32_bf16(AF[0], BF[1], acc[(MO)+0][1], 0,0,0);  \
  acc[(MO)+0][2] = __builtin_amdgcn_mfma_f32_16x16x32_bf16(AF[0], BF[2], acc[(MO)+0][2], 0,0,0);  \
  acc[(MO)+0][3] = __builtin_amdgcn_mfma_f32_16x16x32_bf16(AF[0], BF[3], acc[(MO)+0][3], 0,0,0);  \
  acc[(MO)+1][0] = __builtin_amdgcn_mfma_f32_16x16x32_bf16(AF[1], BF[0], acc[(MO)+1][0], 0,0,0);  \
  acc[(MO)+1][1] = __builtin_amdgcn_mfma_f32_16x16x32_bf16(AF[1], BF[1], acc[(MO)+1][1], 0,0,0);  \
  acc[(MO)+1][2] = __builtin_amdgcn_mfma_f32_16x16x32_bf16(AF[1], BF[2], acc[(MO)+1][2], 0,0,0);  \
  acc[(MO)+1][3] = __builtin_amdgcn_mfma_f32_16x16x32_bf16(AF[1], BF[3], acc[(MO)+1][3], 0,0,0);  \
  acc[(MO)+2][0] = __builtin_amdgcn_mfma_f32_16x16x32_bf16(AF[2], BF[0], acc[(MO)+2][0], 0,0,0);  \
  acc[(MO)+2][1] = __builtin_amdgcn_mfma_f32_16x16x32_bf16(AF[2], BF[1], acc[(MO)+2][1], 0,0,0);  \
  acc[(MO)+2][2] = __builtin_amdgcn_mfma_f32_16x16x32_bf16(AF[2], BF[2], acc[(MO)+2][2], 0,0,0);  \
  acc[(MO)+2][3] = __builtin_amdgcn_mfma_f32_16x16x32_bf16(AF[2], BF[3], acc[(MO)+2][3], 0,0,0);  \
  acc[(MO)+3][0] = __builtin_amdgcn_mfma_f32_16x16x32_bf16(AF[3], BF[0], acc[(MO)+3][0], 0,0,0);  \
  acc[(MO)+3][1] = __builtin_amdgcn_mfma_f32_16x16x32_bf16(AF[3], BF[1], acc[(MO)+3][1], 0,0,0);  \
  acc[(MO)+3][2] = __builtin_amdgcn_mfma_f32_16x16x32_bf16(AF[3], BF[2], acc[(MO)+3][2], 0,0,0);  \
  acc[(MO)+3][3] = __builtin_amdgcn_mfma_f32_16x16x32_bf16(AF[3], BF[3], acc[(MO)+3][3], 0,0,0);

// Body T: computes half2(T) then half1(T+1). S = T&1, SN = (T+1)&1 (literals).
#define GBODY(T, S, SN)                                                        \
  {                                                                            \
    const bf16x8* A8n = (const bf16x8*)(lds + (((T) + 1) & 3) * 16384);        \
    const bf16x8* B8n = A8n + 1024;                                            \
    bv[SN][0]  = B8n[(br +  0) * 4 + csel];                                    \
    bv[SN][1]  = B8n[(br + 16) * 4 + csel];                                    \
    bv[SN][2]  = B8n[(br + 32) * 4 + csel];                                    \
    bv[SN][3]  = B8n[(br + 48) * 4 + csel];                                    \
    a03[SN][0] = A8n[(ar +  0) * 4 + csel];                                    \
    a03[SN][1] = A8n[(ar + 16) * 4 + csel];                                    \
    a03[SN][2] = A8n[(ar + 32) * 4 + csel];                                    \
    a03[SN][3] = A8n[(ar + 48) * 4 + csel];                                    \
    __builtin_amdgcn_sched_barrier(0);                                         \
    ushort_t* sb = lds + (((T) + 3) & 3) * 16384;                              \
    gload_lds16(pA0, sb + ld0);                                                \
    gload_lds16(pA1, sb + ld1);                                                \
    gload_lds16(pB0, sb + 8192 + ld0);                                         \
    gload_lds16(pB1, sb + 8192 + ld1);                                         \
    __builtin_amdgcn_sched_barrier(0);                                         \
    asm volatile("s_waitcnt lgkmcnt(8)" ::: "memory");                         \
    __builtin_amdgcn_sched_barrier(0);                                         \
    __builtin_amdgcn_s_setprio(1);                                             \
    MF16(a47[S], bv[S], 4)                                                     \
    __builtin_amdgcn_s_setprio(0);                                             \
    __builtin_amdgcn_sched_barrier(0);                                         \
    a47[SN][0] = A8n[(ar +  64) * 4 + csel];                                   \
    a47[SN][1] = A8n[(ar +  80) * 4 + csel];                                   \
    a47[SN][2] = A8n[(ar +  96) * 4 + csel];                                   \
    a47[SN][3] = A8n[(ar + 112) * 4 + csel];                                   \
    __builtin_amdgcn_sched_barrier(0);                                         \
    asm volatile("s_waitcnt lgkmcnt(4)" ::: "memory");                         \
    asm volatile("s_waitcnt vmcnt(4)" ::: "memory");                           \
    asm volatile("s_barrier" ::: "memory");                                    \
    __builtin_amdgcn_sched_barrier(0);                                         \
    __builtin_amdgcn_s_setprio(1);                                             \
    MF16(a03[SN], bv[SN], 0)                                                   \
    __builtin_amdgcn_s_setprio(0);                                             \
    __builtin_amdgcn_sched_barrier(0);                                         \
    if ((T) < TILES - 4) { pA0 += 32; pA1 += 32; pB0 += 32; pB1 += 32; }       \
  }

__global__ __launch_bounds__(512, 2) void gemm_bt(const ushort_t* __restrict__ A,
                                                  const ushort_t* __restrict__ B,
                                                  const float* __restrict__ bias,
                                                  float* __restrict__ C) {
  extern __shared__ ushort_t lds[];   // 4 bufs x 32KB = 128KB

  int bid = blockIdx.x;                     // 256 blocks
  int swz = (bid & 7) * 32 + (bid >> 3);    // bijective XCD swizzle
  int bm = swz >> 4;
  int bn = swz & 15;

  int tid  = threadIdx.x;
  int lane = tid & 63;
  int wave = tid >> 6;
  int wm = wave >> 2, wn = wave & 3;        // 2x4 wave grid: 128x64 per wave

  int l15  = lane & 15;
  int csel = (lane >> 4) ^ ((lane >> 1) & 3);

  int idx0 = tid, idx1 = 512 + tid;
  int sr0 = idx0 >> 2, scl0 = (idx0 & 3) ^ ((sr0 >> 1) & 3);
  int sr1 = idx1 >> 2, scl1 = (idx1 & 3) ^ ((sr1 >> 1) & 3);
  int ld0 = idx0 * 8, ld1 = idx1 * 8;
  const ushort_t* pA0 = A + (size_t)(bm * 256 + sr0) * D_IN + scl0 * 8;
  const ushort_t* pA1 = A + (size_t)(bm * 256 + sr1) * D_IN + scl1 * 8;
  const ushort_t* pB0 = B + (size_t)(bn * 256 + sr0) * D_IN + scl0 * 8;
  const ushort_t* pB1 = B + (size_t)(bn * 256 + sr1) * D_IN + scl1 * 8;

  f32x4 acc[8][4];
#pragma unroll
  for (int m = 0; m < 8; m++)
#pragma unroll
    for (int n = 0; n < 4; n++) acc[m][n] = (f32x4){0.f, 0.f, 0.f, 0.f};

  // prologue: stage tiles 0,1,2 (12 gloads)
  gload_lds16(pA0,      lds + ld0);         gload_lds16(pA1,      lds + ld1);
  gload_lds16(pB0,      lds + 8192 + ld0);  gload_lds16(pB1,      lds + 8192 + ld1);
  gload_lds16(pA0 + 32, lds + 16384 + ld0); gload_lds16(pA1 + 32, lds + 16384 + ld1);
  gload_lds16(pB0 + 32, lds + 24576 + ld0); gload_lds16(pB1 + 32, lds + 24576 + ld1);
  gload_lds16(pA0 + 64, lds + 32768 + ld0); gload_lds16(pA1 + 64, lds + 32768 + ld1);
  gload_lds16(pB0 + 64, lds + 40960 + ld0); gload_lds16(pB1 + 64, lds + 40960 + ld1);
  pA0 += 96; pA1 += 96; pB0 += 96; pB1 += 96;   // in-loop staging starts at tile 3
  asm volatile("s_waitcnt vmcnt(4)" ::: "memory");   // tiles 0,1 landed; tile 2 in flight
  asm volatile("s_barrier" ::: "memory");

  int ar = wm * 128 + l15;
  int br = wn * 64 + l15;

  bf16x8 bv[2][4], a03[2][4], a47[2][4];

  // prologue reads for tile 0 (set 0) + half1(0)
  {
    const bf16x8* A8 = (const bf16x8*)lds;
    const bf16x8* B8 = A8 + 1024;
    bv[0][0]  = B8[(br +  0) * 4 + csel];
    bv[0][1]  = B8[(br + 16) * 4 + csel];
    bv[0][2]  = B8[(br + 32) * 4 + csel];
    bv[0][3]  = B8[(br + 48) * 4 + csel];
    a03[0][0] = A8[(ar +  0) * 4 + csel];
    a03[0][1] = A8[(ar + 16) * 4 + csel];
    a03[0][2] = A8[(ar + 32) * 4 + csel];
    a03[0][3] = A8[(ar + 48) * 4 + csel];
    __builtin_amdgcn_sched_barrier(0);
    a47[0][0] = A8[(ar +  64) * 4 + csel];
    a47[0][1] = A8[(ar +  80) * 4 + csel];
    a47[0][2] = A8[(ar +  96) * 4 + csel];
    a47[0][3] = A8[(ar + 112) * 4 + csel];
    __builtin_amdgcn_sched_barrier(0);
    asm volatile("s_waitcnt lgkmcnt(4)" ::: "memory");
    __builtin_amdgcn_sched_barrier(0);
    __builtin_amdgcn_s_setprio(1);
    MF16(a03[0], bv[0], 0)
    __builtin_amdgcn_s_setprio(0);
    __builtin_amdgcn_sched_barrier(0);
  }

  // bodies 0..126 (each computes half2(T) + half1(T+1))
  for (int tt = 0; tt < 63; tt++) {
    int t0 = tt * 2;
    GBODY(t0, 0, 1)
    GBODY(t0 + 1, 1, 0)
  }
  GBODY(126, 0, 1)

  // tail: half2(127)
  asm volatile("s_waitcnt lgkmcnt(0)" ::: "memory");
  __builtin_amdgcn_sched_barrier(0);
  __builtin_amdgcn_s_setprio(1);
  MF16(a47[1], bv[1], 4)
  __builtin_amdgcn_s_setprio(0);

  int orow0 = bm * 256 + wm * 128 + (lane >> 4) * 4;
  int ocol0 = bn * 256 + wn * 64 + l15;
#pragma unroll
  for (int n = 0; n < 4; n++) {
    float bb = bias[ocol0 + n * 16];
#pragma unroll
    for (int m = 0; m < 8; m++) {
#pragma unroll
      for (int r = 0; r < 4; r++) {
        C[(size_t)(orow0 + m * 16 + r) * D_OUT + ocol0 + n * 16] = acc[m][n][r] + bb;
      }
    }
  }
}

// ---------- launch ----------
extern "C" void kernel_launch(void* const* d_in, const int* in_sizes, int n_in,
                              void* d_out, int out_size, void* d_ws, size_t ws_size,
                              hipStream_t stream) {
  const float* x = (const float*)d_in[0];
  const float* w = (const float*)d_in[1];
  const float* bias = (const float*)d_in[2];
  float* out = (float*)d_out;

  char* ws = (char*)d_ws;
  uint32* hist1 = (uint32*)ws;                       // 2048 bins @ 0
  uint32* hs1   = (uint32*)(ws + 8192);              // 1024 bins
  uint32* hs2   = (uint32*)(ws + 12288);             // 1024 bins
  uint32* cnt   = (uint32*)(ws + 16384);             // 1 word
  ushort_t* Xb  = (ushort_t*)(ws + 65536);
  ushort_t* Wb  = (ushort_t*)(ws + 65536 + (size_t)NW * 2);
  uint2*   cand = (uint2*)(ws + 65536 + (size_t)NW * 4);

  hipMemsetAsync(d_ws, 0, 16448, stream);

  k1_hist1_convx<<<5120, 256, 0, stream>>>((const uint4*)w, hist1, (const float4*)x, (uint4*)Xb);
  k2_decide<<<2048, 256, 0, stream>>>((const float4*)w, hist1, (uint4*)Wb, cand, cnt, hs1);
  s2_hist<<<128, 256, 0, stream>>>(cand, cnt, hist1, hs1, hs2);
  k5_fixup<<<256, 256, 0, stream>>>(cand, cnt, hist1, hs1, hs2, Wb);

  gemm_bt<<<256, 512, 131072, stream>>>(Xb, Wb, bias, out);
}

// Round 10
// 222.150 us; speedup vs baseline: 1.0461x; 1.0461x over previous
//
#include <hip/hip_runtime.h>
#include <stdint.h>

#define D_IN   4096
#define D_OUT  4096
#define NTOK   4096
#define NW     (D_OUT * D_IN)          // 16777216
#define RANK1  15099493u               // floor(0.9f * (NW-1)) as jax computes in f32
#define CAP    1500000                 // candidate list capacity (expected ~700K)

typedef unsigned int  uint32;
typedef unsigned short ushort_t;
typedef float  f32x16 __attribute__((ext_vector_type(16)));
typedef __bf16 bf16x8 __attribute__((ext_vector_type(8)));

// ---------- helpers ----------
__device__ __forceinline__ uint32 rne_bf16(float f) {
  uint32 u = __float_as_uint(f);
  return (u + 0x7FFFu + ((u >> 16) & 1u)) >> 16;
}

__device__ __forceinline__ void gload_lds16(const void* g, void* l) {
  __builtin_amdgcn_global_load_lds((__attribute__((address_space(1))) void*)(g),
                                   (__attribute__((address_space(3))) void*)(l), 16, 0, 0);
}

// block-redundant select: find bin containing `rank` in NB-bin global histogram.
template <int NB>
__device__ __forceinline__ void dsel(const uint32* __restrict__ h, uint32 rank,
                                     uint32* res, uint32* wtot) {
  constexpr int PER = NB >> 8;
  int tid = threadIdx.x;
  int lane = tid & 63, wid = tid >> 6;
  uint32 loc[PER];
  uint32 s = 0;
  int base = tid * PER;
#pragma unroll
  for (int i = 0; i < PER; i++) { loc[i] = h[base + i]; s += loc[i]; }
  uint32 v = s;
  for (int d = 1; d < 64; d <<= 1) { uint32 o = __shfl_up(v, (unsigned)d); if (lane >= d) v += o; }
  if (lane == 63) wtot[wid] = v;
  __syncthreads();
  uint32 woff = 0;
  for (int w = 0; w < wid; w++) woff += wtot[w];
  uint32 incl = v + woff, excl = incl - s;
  if (rank >= excl && rank < incl) {
    uint32 c = excl;
#pragma unroll
    for (int i = 0; i < PER; i++) {
      if (rank < c + loc[i]) { res[0] = (uint32)(base + i); res[1] = rank - c; break; }
      c += loc[i];
    }
  }
  __syncthreads();
}

// ---------- K1: hist pass 1 (blocks 0..2047) + convert_x (blocks 2048..3071) ----------
__global__ void k1_hist1_convx(const uint4* __restrict__ wb, uint32* __restrict__ hist,
                               const float4* __restrict__ x, uint4* __restrict__ xout) {
  __shared__ uint32 lh[4][2048];
  if (blockIdx.x < 2048) {
    for (int i = threadIdx.x; i < 8192; i += 256) ((uint32*)lh)[i] = 0;
    __syncthreads();
    int wid = threadIdx.x >> 6;
    int idx = blockIdx.x * 256 + threadIdx.x;
    for (int i = idx; i < NW / 4; i += 2048 * 256) {
      uint4 v = wb[i];
      atomicAdd(&lh[wid][(v.x & 0x7FFFFFFFu) >> 20], 1u);
      atomicAdd(&lh[wid][(v.y & 0x7FFFFFFFu) >> 20], 1u);
      atomicAdd(&lh[wid][(v.z & 0x7FFFFFFFu) >> 20], 1u);
      atomicAdd(&lh[wid][(v.w & 0x7FFFFFFFu) >> 20], 1u);
    }
    __syncthreads();
    for (int i = threadIdx.x; i < 2048; i += 256) {
      uint32 c = lh[0][i] + lh[1][i] + lh[2][i] + lh[3][i];
      if (c) atomicAdd(&hist[i], c);
    }
  } else {
    int i = (blockIdx.x - 2048) * 256 + threadIdx.x;
    for (; i < NW / 8; i += 1024 * 256) {
      float4 a = x[2 * i], b = x[2 * i + 1];
      uint4 o;
      o.x = rne_bf16(a.x) | (rne_bf16(a.y) << 16);
      o.y = rne_bf16(a.z) | (rne_bf16(a.w) << 16);
      o.z = rne_bf16(b.x) | (rne_bf16(b.y) << 16);
      o.w = rne_bf16(b.z) | (rne_bf16(b.w) << 16);
      xout[i] = o;
    }
  }
}

// ---------- K2: decide + convert W + compact candidates + FUSED s1 hist ----------
__global__ void k2_decide(const float4* __restrict__ w, const uint32* __restrict__ hist1,
                          uint4* __restrict__ out, uint2* __restrict__ cand,
                          uint32* __restrict__ cnt, uint32* __restrict__ hs1) {
  __shared__ uint32 res1[2], wt[4];
  __shared__ uint32 lcnt, lbase;
  __shared__ uint2 lbuf[3072];
  __shared__ uint32 lch[1024];
  for (int i = threadIdx.x; i < 1024; i += 256) lch[i] = 0;
  if (threadIdx.x == 0) lcnt = 0;
  dsel<2048>(hist1, RANK1, res1, wt);          // internal syncthreads orders the zeroing
  uint32 bstar = res1[0];
  int i = blockIdx.x * 256 + threadIdx.x;
  for (; i < NW / 8; i += 512 * 256) {
    float4 a = w[2 * i], b = w[2 * i + 1];
    float f[8] = {a.x, a.y, a.z, a.w, b.x, b.y, b.z, b.w};
    uint32 h[8];
#pragma unroll
    for (int j = 0; j < 8; j++) {
      uint32 bits = __float_as_uint(f[j]);
      uint32 bin = (bits & 0x7FFFFFFFu) >> 20;
      h[j] = (bin > bstar) ? rne_bf16(f[j]) : 0u;
      if (bin == bstar) {
        uint32 p = atomicAdd(&lcnt, 1u);
        if (p < 3072) {
          lbuf[p] = make_uint2((uint32)(8 * i + j), bits);
          atomicAdd(&lch[(bits >> 10) & 1023u], 1u);
        }
      }
    }
    uint4 o;
    o.x = h[0] | (h[1] << 16);
    o.y = h[2] | (h[3] << 16);
    o.z = h[4] | (h[5] << 16);
    o.w = h[6] | (h[7] << 16);
    out[i] = o;
  }
  __syncthreads();
  uint32 nstore = lcnt < 3072u ? lcnt : 3072u;
  if (threadIdx.x == 0) lbase = atomicAdd(cnt, nstore);
  __syncthreads();
  for (uint32 p = threadIdx.x; p < nstore; p += 256) {
    uint32 g = lbase + p;
    if (g < CAP) cand[g] = lbuf[p];
  }
  for (int ii = threadIdx.x; ii < 1024; ii += 256) if (lch[ii]) atomicAdd(&hs1[ii], lch[ii]);
}

// ---------- S2: filter on bits[19:10], hist bits [9:0] ----------
__global__ void s2_hist(const uint2* __restrict__ cand, const uint32* __restrict__ cnt,
                        const uint32* __restrict__ hist1, const uint32* __restrict__ hs1,
                        uint32* __restrict__ hs2) {
  __shared__ uint32 lh[1024];
  __shared__ uint32 res1[2], res2[2], wt[4];
  for (int i = threadIdx.x; i < 1024; i += 256) lh[i] = 0;
  dsel<2048>(hist1, RANK1, res1, wt);
  dsel<1024>(hs1, res1[1], res2, wt);
  uint32 b2 = res2[0];
  uint32 n = *cnt; if (n > CAP) n = CAP;
  for (uint32 i = blockIdx.x * 256 + threadIdx.x; i < n; i += gridDim.x * 256) {
    uint32 mag = cand[i].y & 0x7FFFFFFFu;
    if (((mag >> 10) & 1023u) == b2) atomicAdd(&lh[mag & 1023u], 1u);
  }
  __syncthreads();
  for (int i = threadIdx.x; i < 1024; i += 256) if (lh[i]) atomicAdd(&hs2[i], lh[i]);
}

// ---------- K5: final threshold, fix up kept candidates ----------
__global__ void k5_fixup(const uint2* __restrict__ cand, const uint32* __restrict__ cnt,
                         const uint32* __restrict__ hist1, const uint32* __restrict__ hs1,
                         const uint32* __restrict__ hs2, ushort_t* __restrict__ wb) {
  __shared__ uint32 res1[2], res2[2], res3[2], wt[4];
  dsel<2048>(hist1, RANK1, res1, wt);
  dsel<1024>(hs1, res1[1], res2, wt);
  dsel<1024>(hs2, res2[1], res3, wt);
  uint32 thr_mag = (res1[0] << 20) | (res2[0] << 10) | res3[0];
  uint32 n = *cnt; if (n > CAP) n = CAP;
  for (uint32 i = blockIdx.x * 256 + threadIdx.x; i < n; i += gridDim.x * 256) {
    uint2 c = cand[i];
    uint32 mag = c.y & 0x7FFFFFFFu;
    if (mag > thr_mag) wb[c.x] = (ushort_t)rne_bf16(__uint_as_float(c.y));
  }
}

// ---------- GEMM: C[M,N] = Xb[M,K] * Wb[N,K]^T + bias ----------
// R5 schedule skeleton (proven: quad-buffered LDS, stage-3-ahead, lgkm(8)/
// lgkm(4)+vmcnt(4) counted waits, one barrier/K-tile) with MFMA shape switched
// 16x16x32 -> 32x32x16 (m119: 2495 vs ~2100 TF ceiling, ~17% less matrix-pipe
// time; same 12 ds_read_b128/wave/K-tile; same swizzle, still <=2-way banks).
// Per wave: 4x2 blocks of 32x32, acc = 8 x f32x16.
#define TILES 128

#define MFMA32(A, B, ACC) __builtin_amdgcn_mfma_f32_32x32x16_bf16(A, B, ACC, 0, 0, 0)

#define MF8(AF, B0, B1)                    \
  acc[0] = MFMA32(AF[0], B0, acc[0]);      \
  acc[1] = MFMA32(AF[0], B1, acc[1]);      \
  acc[2] = MFMA32(AF[1], B0, acc[2]);      \
  acc[3] = MFMA32(AF[1], B1, acc[3]);      \
  acc[4] = MFMA32(AF[2], B0, acc[4]);      \
  acc[5] = MFMA32(AF[2], B1, acc[5]);      \
  acc[6] = MFMA32(AF[3], B0, acc[6]);      \
  acc[7] = MFMA32(AF[3], B1, acc[7]);

// Body T: computes s=1 half of tile T, then s=0 half of tile T+1.
#define GBODY(T, S, SN)                                                        \
  {                                                                            \
    const bf16x8* A8n = (const bf16x8*)(lds + (((T) + 1) & 3) * 16384);        \
    const bf16x8* B8n = A8n + 1024;                                            \
    bv[SN][0]   = B8n[(br +  0) * 4 + cs0];                                    \
    bv[SN][1]   = B8n[(br +  0) * 4 + cs1];                                    \
    bv[SN][2]   = B8n[(br + 32) * 4 + cs0];                                    \
    bv[SN][3]   = B8n[(br + 32) * 4 + cs1];                                    \
    afs0[SN][0] = A8n[(ar +  0) * 4 + cs0];                                    \
    afs0[SN][1] = A8n[(ar + 32) * 4 + cs0];                                    \
    afs0[SN][2] = A8n[(ar + 64) * 4 + cs0];                                    \
    afs0[SN][3] = A8n[(ar + 96) * 4 + cs0];                                    \
    __builtin_amdgcn_sched_barrier(0);                                         \
    ushort_t* sb = lds + (((T) + 3) & 3) * 16384;                              \
    gload_lds16(pA0, sb + ld0);                                                \
    gload_lds16(pA1, sb + ld1);                                                \
    gload_lds16(pB0, sb + 8192 + ld0);                                         \
    gload_lds16(pB1, sb + 8192 + ld1);                                         \
    __builtin_amdgcn_sched_barrier(0);                                         \
    asm volatile("s_waitcnt lgkmcnt(8)" ::: "memory");                         \
    __builtin_amdgcn_sched_barrier(0);                                         \
    __builtin_amdgcn_s_setprio(1);                                             \
    MF8(afs1[S], bv[S][1], bv[S][3])                                           \
    __builtin_amdgcn_s_setprio(0);                                             \
    __builtin_amdgcn_sched_barrier(0);                                         \
    afs1[SN][0] = A8n[(ar +  0) * 4 + cs1];                                    \
    afs1[SN][1] = A8n[(ar + 32) * 4 + cs1];                                    \
    afs1[SN][2] = A8n[(ar + 64) * 4 + cs1];                                    \
    afs1[SN][3] = A8n[(ar + 96) * 4 + cs1];                                    \
    __builtin_amdgcn_sched_barrier(0);                                         \
    asm volatile("s_waitcnt lgkmcnt(4)" ::: "memory");                         \
    asm volatile("s_waitcnt vmcnt(4)" ::: "memory");                           \
    asm volatile("s_barrier" ::: "memory");                                    \
    __builtin_amdgcn_sched_barrier(0);                                         \
    __builtin_amdgcn_s_setprio(1);                                             \
    MF8(afs0[SN], bv[SN][0], bv[SN][2])                                        \
    __builtin_amdgcn_s_setprio(0);                                             \
    __builtin_amdgcn_sched_barrier(0);                                         \
    if ((T) < TILES - 4) { pA0 += 32; pA1 += 32; pB0 += 32; pB1 += 32; }       \
  }

__global__ __launch_bounds__(512, 2) void gemm_bt(const ushort_t* __restrict__ A,
                                                  const ushort_t* __restrict__ B,
                                                  const float* __restrict__ bias,
                                                  float* __restrict__ C) {
  extern __shared__ ushort_t lds[];   // 4 bufs x 32KB = 128KB

  int bid = blockIdx.x;                     // 256 blocks
  int swz = (bid & 7) * 32 + (bid >> 3);    // bijective XCD swizzle
  int bm = swz >> 4;
  int bn = swz & 15;

  int tid  = threadIdx.x;
  int lane = tid & 63;
  int wave = tid >> 6;
  int wm = wave >> 2, wn = wave & 3;        // 2x4 wave grid: 128x64 per wave

  int l31  = lane & 31;
  int xr   = (lane >> 1) & 3;
  int kc   = lane >> 5;                     // 0/1: which K-half of the chunk pair
  int cs0  = kc ^ xr;                       // physical chunk for s=0 (swizzled)
  int cs1  = cs0 ^ 2;                       // physical chunk for s=1

  int idx0 = tid, idx1 = 512 + tid;
  int sr0 = idx0 >> 2, scl0 = (idx0 & 3) ^ ((sr0 >> 1) & 3);
  int sr1 = idx1 >> 2, scl1 = (idx1 & 3) ^ ((sr1 >> 1) & 3);
  int ld0 = idx0 * 8, ld1 = idx1 * 8;
  const ushort_t* pA0 = A + (size_t)(bm * 256 + sr0) * D_IN + scl0 * 8;
  const ushort_t* pA1 = A + (size_t)(bm * 256 + sr1) * D_IN + scl1 * 8;
  const ushort_t* pB0 = B + (size_t)(bn * 256 + sr0) * D_IN + scl0 * 8;
  const ushort_t* pB1 = B + (size_t)(bn * 256 + sr1) * D_IN + scl1 * 8;

  f32x16 acc[8];
#pragma unroll
  for (int m = 0; m < 8; m++)
#pragma unroll
    for (int r = 0; r < 16; r++) acc[m][r] = 0.f;

  // prologue: stage tiles 0,1,2 (12 gloads)
  gload_lds16(pA0,      lds + ld0);         gload_lds16(pA1,      lds + ld1);
  gload_lds16(pB0,      lds + 8192 + ld0);  gload_lds16(pB1,      lds + 8192 + ld1);
  gload_lds16(pA0 + 32, lds + 16384 + ld0); gload_lds16(pA1 + 32, lds + 16384 + ld1);
  gload_lds16(pB0 + 32, lds + 24576 + ld0); gload_lds16(pB1 + 32, lds + 24576 + ld1);
  gload_lds16(pA0 + 64, lds + 32768 + ld0); gload_lds16(pA1 + 64, lds + 32768 + ld1);
  gload_lds16(pB0 + 64, lds + 40960 + ld0); gload_lds16(pB1 + 64, lds + 40960 + ld1);
  pA0 += 96; pA1 += 96; pB0 += 96; pB1 += 96;   // in-loop staging starts at tile 3
  asm volatile("s_waitcnt vmcnt(4)" ::: "memory");   // tiles 0,1 landed; tile 2 in flight
  asm volatile("s_barrier" ::: "memory");

  int ar = wm * 128 + l31;
  int br = wn * 64 + l31;

  bf16x8 bv[2][4], afs0[2][4], afs1[2][4];

  // prologue reads for tile 0 (set 0) + s=0 half of tile 0
  {
    const bf16x8* A8 = (const bf16x8*)lds;
    const bf16x8* B8 = A8 + 1024;
    bv[0][0]   = B8[(br +  0) * 4 + cs0];
    bv[0][1]   = B8[(br +  0) * 4 + cs1];
    bv[0][2]   = B8[(br + 32) * 4 + cs0];
    bv[0][3]   = B8[(br + 32) * 4 + cs1];
    afs0[0][0] = A8[(ar +  0) * 4 + cs0];
    afs0[0][1] = A8[(ar + 32) * 4 + cs0];
    afs0[0][2] = A8[(ar + 64) * 4 + cs0];
    afs0[0][3] = A8[(ar + 96) * 4 + cs0];
    __builtin_amdgcn_sched_barrier(0);
    afs1[0][0] = A8[(ar +  0) * 4 + cs1];
    afs1[0][1] = A8[(ar + 32) * 4 + cs1];
    afs1[0][2] = A8[(ar + 64) * 4 + cs1];
    afs1[0][3] = A8[(ar + 96) * 4 + cs1];
    __builtin_amdgcn_sched_barrier(0);
    asm volatile("s_waitcnt lgkmcnt(4)" ::: "memory");
    __builtin_amdgcn_sched_barrier(0);
    __builtin_amdgcn_s_setprio(1);
    MF8(afs0[0], bv[0][0], bv[0][2])
    __builtin_amdgcn_s_setprio(0);
    __builtin_amdgcn_sched_barrier(0);
  }

  // bodies 0..126 (each computes s1(T) + s0(T+1))
  for (int tt = 0; tt < 63; tt++) {
    int t0 = tt * 2;
    GBODY(t0, 0, 1)
    GBODY(t0 + 1, 1, 0)
  }
  GBODY(126, 0, 1)

  // tail: s=1 half of tile 127
  asm volatile("s_waitcnt lgkmcnt(0)" ::: "memory");
  __builtin_amdgcn_sched_barrier(0);
  __builtin_amdgcn_s_setprio(1);
  MF8(afs1[1], bv[1][1], bv[1][3])
  __builtin_amdgcn_s_setprio(0);

  // writeout: 32x32 C/D layout (verified m74/m101):
  // col = lane&31, row = (r&3) + 8*(r>>2) + 4*(lane>>5), r in [0,16)
  int orow0 = bm * 256 + wm * 128 + 4 * (lane >> 5);
  int ocol0 = bn * 256 + wn * 64 + l31;
#pragma unroll
  for (int ni = 0; ni < 2; ni++) {
    float bb = bias[ocol0 + ni * 32];
#pragma unroll
    for (int mi = 0; mi < 4; mi++) {
#pragma unroll
      for (int r = 0; r < 16; r++) {
        int row = orow0 + mi * 32 + (r & 3) + 8 * (r >> 2);
        C[(size_t)row * D_OUT + ocol0 + ni * 32] = acc[mi * 2 + ni][r] + bb;
      }
    }
  }
}

// ---------- launch ----------
extern "C" void kernel_launch(void* const* d_in, const int* in_sizes, int n_in,
                              void* d_out, int out_size, void* d_ws, size_t ws_size,
                              hipStream_t stream) {
  const float* x = (const float*)d_in[0];
  const float* w = (const float*)d_in[1];
  const float* bias = (const float*)d_in[2];
  float* out = (float*)d_out;

  char* ws = (char*)d_ws;
  uint32* hist1 = (uint32*)ws;                       // 2048 bins @ 0
  uint32* hs1   = (uint32*)(ws + 8192);              // 1024 bins
  uint32* hs2   = (uint32*)(ws + 12288);             // 1024 bins
  uint32* cnt   = (uint32*)(ws + 16384);             // 1 word
  ushort_t* Xb  = (ushort_t*)(ws + 65536);
  ushort_t* Wb  = (ushort_t*)(ws + 65536 + (size_t)NW * 2);
  uint2*   cand = (uint2*)(ws + 65536 + (size_t)NW * 4);

  hipMemsetAsync(d_ws, 0, 16448, stream);

  k1_hist1_convx<<<3072, 256, 0, stream>>>((const uint4*)w, hist1, (const float4*)x, (uint4*)Xb);
  k2_decide<<<512, 256, 0, stream>>>((const float4*)w, hist1, (uint4*)Wb, cand, cnt, hs1);
  s2_hist<<<128, 256, 0, stream>>>(cand, cnt, hist1, hs1, hs2);
  k5_fixup<<<256, 256, 0, stream>>>(cand, cnt, hist1, hs1, hs2, Wb);

  gemm_bt<<<256, 512, 131072, stream>>>(Xb, Wb, bias, out);
}

// Round 11
// 214.142 us; speedup vs baseline: 1.0852x; 1.0374x over previous
//
#include <hip/hip_runtime.h>
#include <stdint.h>

#define D_IN   4096
#define D_OUT  4096
#define NTOK   4096
#define NW     (D_OUT * D_IN)          // 16777216
#define RANK1  15099493u               // floor(0.9f * (NW-1)) as jax computes in f32
#define CAP    1500000                 // candidate list capacity (expected ~700K)

typedef unsigned int  uint32;
typedef unsigned short ushort_t;
typedef float  f32x4  __attribute__((ext_vector_type(4)));
typedef __bf16 bf16x8 __attribute__((ext_vector_type(8)));

// ---------- helpers ----------
__device__ __forceinline__ uint32 rne_bf16(float f) {
  uint32 u = __float_as_uint(f);
  return (u + 0x7FFFu + ((u >> 16) & 1u)) >> 16;
}

__device__ __forceinline__ void gload_lds16(const void* g, void* l) {
  __builtin_amdgcn_global_load_lds((__attribute__((address_space(1))) void*)(g),
                                   (__attribute__((address_space(3))) void*)(l), 16, 0, 0);
}

// block-redundant select: find bin containing `rank` in NB-bin global histogram.
template <int NB>
__device__ __forceinline__ void dsel(const uint32* __restrict__ h, uint32 rank,
                                     uint32* res, uint32* wtot) {
  constexpr int PER = NB >> 8;
  int tid = threadIdx.x;
  int lane = tid & 63, wid = tid >> 6;
  uint32 loc[PER];
  uint32 s = 0;
  int base = tid * PER;
#pragma unroll
  for (int i = 0; i < PER; i++) { loc[i] = h[base + i]; s += loc[i]; }
  uint32 v = s;
  for (int d = 1; d < 64; d <<= 1) { uint32 o = __shfl_up(v, (unsigned)d); if (lane >= d) v += o; }
  if (lane == 63) wtot[wid] = v;
  __syncthreads();
  uint32 woff = 0;
  for (int w = 0; w < wid; w++) woff += wtot[w];
  uint32 incl = v + woff, excl = incl - s;
  if (rank >= excl && rank < incl) {
    uint32 c = excl;
#pragma unroll
    for (int i = 0; i < PER; i++) {
      if (rank < c + loc[i]) { res[0] = (uint32)(base + i); res[1] = rank - c; break; }
      c += loc[i];
    }
  }
  __syncthreads();
}

// ---------- K1: hist pass 1 (blocks 0..2047) + convert_x (blocks 2048..3071) ----------
__global__ void k1_hist1_convx(const uint4* __restrict__ wb, uint32* __restrict__ hist,
                               const float4* __restrict__ x, uint4* __restrict__ xout) {
  __shared__ uint32 lh[4][2048];
  if (blockIdx.x < 2048) {
    for (int i = threadIdx.x; i < 8192; i += 256) ((uint32*)lh)[i] = 0;
    __syncthreads();
    int wid = threadIdx.x >> 6;
    int idx = blockIdx.x * 256 + threadIdx.x;
    for (int i = idx; i < NW / 4; i += 2048 * 256) {
      uint4 v = wb[i];
      atomicAdd(&lh[wid][(v.x & 0x7FFFFFFFu) >> 20], 1u);
      atomicAdd(&lh[wid][(v.y & 0x7FFFFFFFu) >> 20], 1u);
      atomicAdd(&lh[wid][(v.z & 0x7FFFFFFFu) >> 20], 1u);
      atomicAdd(&lh[wid][(v.w & 0x7FFFFFFFu) >> 20], 1u);
    }
    __syncthreads();
    for (int i = threadIdx.x; i < 2048; i += 256) {
      uint32 c = lh[0][i] + lh[1][i] + lh[2][i] + lh[3][i];
      if (c) atomicAdd(&hist[i], c);
    }
  } else {
    int i = (blockIdx.x - 2048) * 256 + threadIdx.x;
    for (; i < NW / 8; i += 1024 * 256) {
      float4 a = x[2 * i], b = x[2 * i + 1];
      uint4 o;
      o.x = rne_bf16(a.x) | (rne_bf16(a.y) << 16);
      o.y = rne_bf16(a.z) | (rne_bf16(a.w) << 16);
      o.z = rne_bf16(b.x) | (rne_bf16(b.y) << 16);
      o.w = rne_bf16(b.z) | (rne_bf16(b.w) << 16);
      xout[i] = o;
    }
  }
}

// ---------- K2: decide + convert W + compact candidates + FUSED s1 hist ----------
__global__ void k2_decide(const float4* __restrict__ w, const uint32* __restrict__ hist1,
                          uint4* __restrict__ out, uint2* __restrict__ cand,
                          uint32* __restrict__ cnt, uint32* __restrict__ hs1) {
  __shared__ uint32 res1[2], wt[4];
  __shared__ uint32 lcnt, lbase;
  __shared__ uint2 lbuf[3072];
  __shared__ uint32 lch[1024];
  for (int i = threadIdx.x; i < 1024; i += 256) lch[i] = 0;
  if (threadIdx.x == 0) lcnt = 0;
  dsel<2048>(hist1, RANK1, res1, wt);          // internal syncthreads orders the zeroing
  uint32 bstar = res1[0];
  int i = blockIdx.x * 256 + threadIdx.x;
  for (; i < NW / 8; i += 512 * 256) {
    float4 a = w[2 * i], b = w[2 * i + 1];
    float f[8] = {a.x, a.y, a.z, a.w, b.x, b.y, b.z, b.w};
    uint32 h[8];
#pragma unroll
    for (int j = 0; j < 8; j++) {
      uint32 bits = __float_as_uint(f[j]);
      uint32 bin = (bits & 0x7FFFFFFFu) >> 20;
      h[j] = (bin > bstar) ? rne_bf16(f[j]) : 0u;
      if (bin == bstar) {
        uint32 p = atomicAdd(&lcnt, 1u);
        if (p < 3072) {
          lbuf[p] = make_uint2((uint32)(8 * i + j), bits);
          atomicAdd(&lch[(bits >> 10) & 1023u], 1u);
        }
      }
    }
    uint4 o;
    o.x = h[0] | (h[1] << 16);
    o.y = h[2] | (h[3] << 16);
    o.z = h[4] | (h[5] << 16);
    o.w = h[6] | (h[7] << 16);
    out[i] = o;
  }
  __syncthreads();
  uint32 nstore = lcnt < 3072u ? lcnt : 3072u;
  if (threadIdx.x == 0) lbase = atomicAdd(cnt, nstore);
  __syncthreads();
  for (uint32 p = threadIdx.x; p < nstore; p += 256) {
    uint32 g = lbase + p;
    if (g < CAP) cand[g] = lbuf[p];
  }
  for (int ii = threadIdx.x; ii < 1024; ii += 256) if (lch[ii]) atomicAdd(&hs1[ii], lch[ii]);
}

// ---------- S2: filter on bits[19:10], hist bits [9:0] ----------
__global__ void s2_hist(const uint2* __restrict__ cand, const uint32* __restrict__ cnt,
                        const uint32* __restrict__ hist1, const uint32* __restrict__ hs1,
                        uint32* __restrict__ hs2) {
  __shared__ uint32 lh[1024];
  __shared__ uint32 res1[2], res2[2], wt[4];
  for (int i = threadIdx.x; i < 1024; i += 256) lh[i] = 0;
  dsel<2048>(hist1, RANK1, res1, wt);
  dsel<1024>(hs1, res1[1], res2, wt);
  uint32 b2 = res2[0];
  uint32 n = *cnt; if (n > CAP) n = CAP;
  for (uint32 i = blockIdx.x * 256 + threadIdx.x; i < n; i += gridDim.x * 256) {
    uint32 mag = cand[i].y & 0x7FFFFFFFu;
    if (((mag >> 10) & 1023u) == b2) atomicAdd(&lh[mag & 1023u], 1u);
  }
  __syncthreads();
  for (int i = threadIdx.x; i < 1024; i += 256) if (lh[i]) atomicAdd(&hs2[i], lh[i]);
}

// ---------- K5: final threshold, fix up kept candidates ----------
__global__ void k5_fixup(const uint2* __restrict__ cand, const uint32* __restrict__ cnt,
                         const uint32* __restrict__ hist1, const uint32* __restrict__ hs1,
                         const uint32* __restrict__ hs2, ushort_t* __restrict__ wb) {
  __shared__ uint32 res1[2], res2[2], res3[2], wt[4];
  dsel<2048>(hist1, RANK1, res1, wt);
  dsel<1024>(hs1, res1[1], res2, wt);
  dsel<1024>(hs2, res2[1], res3, wt);
  uint32 thr_mag = (res1[0] << 20) | (res2[0] << 10) | res3[0];
  uint32 n = *cnt; if (n > CAP) n = CAP;
  for (uint32 i = blockIdx.x * 256 + threadIdx.x; i < n; i += gridDim.x * 256) {
    uint2 c = cand[i];
    uint32 mag = c.y & 0x7FFFFFFFu;
    if (mag > thr_mag) wb[c.x] = (ushort_t)rne_bf16(__uint_as_float(c.y));
  }
}

// ---------- GEMM: C[M,N] = Xb[M,K] * Wb[N,K]^T + bias ----------
// PROVEN R5 structure (103.2-103.5 us, MfmaUtil ~58%, reproduced 3x): 256x256
// tile, BK=32, 8 waves (2x4), QUAD-buffered LDS (128KB), stage 3-ahead,
// software-pipelined frag reads; each MFMA burst runs with 4-8 ds_reads in
// flight for the NEXT half-tile. One barrier + one counted vmcnt(4) per K-tile.
#define TILES 128

#define MF16(AF, BF, MO)                                                                          \
  acc[(MO)+0][0] = __builtin_amdgcn_mfma_f32_16x16x32_bf16(AF[0], BF[0], acc[(MO)+0][0], 0,0,0);  \
  acc[(MO)+0][1] = __builtin_amdgcn_mfma_f32_16x16x32_bf16(AF[0], BF[1], acc[(MO)+0][1], 0,0,0);  \
  acc[(MO)+0][2] = __builtin_amdgcn_mfma_f32_16x16x32_bf16(AF[0], BF[2], acc[(MO)+0][2], 0,0,0);  \
  acc[(MO)+0][3] = __builtin_amdgcn_mfma_f32_16x16x32_bf16(AF[0], BF[3], acc[(MO)+0][3], 0,0,0);  \
  acc[(MO)+1][0] = __builtin_amdgcn_mfma_f32_16x16x32_bf16(AF[1], BF[0], acc[(MO)+1][0], 0,0,0);  \
  acc[(MO)+1][1] = __builtin_amdgcn_mfma_f32_16x16x32_bf16(AF[1], BF[1], acc[(MO)+1][1], 0,0,0);  \
  acc[(MO)+1][2] = __builtin_amdgcn_mfma_f32_16x16x32_bf16(AF[1], BF[2], acc[(MO)+1][2], 0,0,0);  \
  acc[(MO)+1][3] = __builtin_amdgcn_mfma_f32_16x16x32_bf16(AF[1], BF[3], acc[(MO)+1][3], 0,0,0);  \
  acc[(MO)+2][0] = __builtin_amdgcn_mfma_f32_16x16x32_bf16(AF[2], BF[0], acc[(MO)+2][0], 0,0,0);  \
  acc[(MO)+2][1] = __builtin_amdgcn_mfma_f32_16x16x32_bf16(AF[2], BF[1], acc[(MO)+2][1], 0,0,0);  \
  acc[(MO)+2][2] = __builtin_amdgcn_mfma_f32_16x16x32_bf16(AF[2], BF[2], acc[(MO)+2][2], 0,0,0);  \
  acc[(MO)+2][3] = __builtin_amdgcn_mfma_f32_16x16x32_bf16(AF[2], BF[3], acc[(MO)+2][3], 0,0,0);  \
  acc[(MO)+3][0] = __builtin_amdgcn_mfma_f32_16x16x32_bf16(AF[3], BF[0], acc[(MO)+3][0], 0,0,0);  \
  acc[(MO)+3][1] = __builtin_amdgcn_mfma_f32_16x16x32_bf16(AF[3], BF[1], acc[(MO)+3][1], 0,0,0);  \
  acc[(MO)+3][2] = __builtin_amdgcn_mfma_f32_16x16x32_bf16(AF[3], BF[2], acc[(MO)+3][2], 0,0,0);  \
  acc[(MO)+3][3] = __builtin_amdgcn_mfma_f32_16x16x32_bf16(AF[3], BF[3], acc[(MO)+3][3], 0,0,0);

// Body T: computes half2(T) then half1(T+1). S = T&1, SN = (T+1)&1 (literals).
#define GBODY(T, S, SN)                                                        \
  {                                                                            \
    const bf16x8* A8n = (const bf16x8*)(lds + (((T) + 1) & 3) * 16384);        \
    const bf16x8* B8n = A8n + 1024;                                            \
    bv[SN][0]  = B8n[(br +  0) * 4 + csel];                                    \
    bv[SN][1]  = B8n[(br + 16) * 4 + csel];                                    \
    bv[SN][2]  = B8n[(br + 32) * 4 + csel];                                    \
    bv[SN][3]  = B8n[(br + 48) * 4 + csel];                                    \
    a03[SN][0] = A8n[(ar +  0) * 4 + csel];                                    \
    a03[SN][1] = A8n[(ar + 16) * 4 + csel];                                    \
    a03[SN][2] = A8n[(ar + 32) * 4 + csel];                                    \
    a03[SN][3] = A8n[(ar + 48) * 4 + csel];                                    \
    __builtin_amdgcn_sched_barrier(0);                                         \
    ushort_t* sb = lds + (((T) + 3) & 3) * 16384;                              \
    gload_lds16(pA0, sb + ld0);                                                \
    gload_lds16(pA1, sb + ld1);                                                \
    gload_lds16(pB0, sb + 8192 + ld0);                                         \
    gload_lds16(pB1, sb + 8192 + ld1);                                         \
    __builtin_amdgcn_sched_barrier(0);                                         \
    asm volatile("s_waitcnt lgkmcnt(8)" ::: "memory");                         \
    __builtin_amdgcn_sched_barrier(0);                                         \
    __builtin_amdgcn_s_setprio(1);                                             \
    MF16(a47[S], bv[S], 4)                                                     \
    __builtin_amdgcn_s_setprio(0);                                             \
    __builtin_amdgcn_sched_barrier(0);                                         \
    a47[SN][0] = A8n[(ar +  64) * 4 + csel];                                   \
    a47[SN][1] = A8n[(ar +  80) * 4 + csel];                                   \
    a47[SN][2] = A8n[(ar +  96) * 4 + csel];                                   \
    a47[SN][3] = A8n[(ar + 112) * 4 + csel];                                   \
    __builtin_amdgcn_sched_barrier(0);                                         \
    asm volatile("s_waitcnt lgkmcnt(4)" ::: "memory");                         \
    asm volatile("s_waitcnt vmcnt(4)" ::: "memory");                           \
    asm volatile("s_barrier" ::: "memory");                                    \
    __builtin_amdgcn_sched_barrier(0);                                         \
    __builtin_amdgcn_s_setprio(1);                                             \
    MF16(a03[SN], bv[SN], 0)                                                   \
    __builtin_amdgcn_s_setprio(0);                                             \
    __builtin_amdgcn_sched_barrier(0);                                         \
    if ((T) < TILES - 4) { pA0 += 32; pA1 += 32; pB0 += 32; pB1 += 32; }       \
  }

__global__ __launch_bounds__(512, 2) void gemm_bt(const ushort_t* __restrict__ A,
                                                  const ushort_t* __restrict__ B,
                                                  const float* __restrict__ bias,
                                                  float* __restrict__ C) {
  extern __shared__ ushort_t lds[];   // 4 bufs x 32KB = 128KB

  int bid = blockIdx.x;                     // 256 blocks
  int swz = (bid & 7) * 32 + (bid >> 3);    // bijective XCD swizzle
  int bm = swz >> 4;
  int bn = swz & 15;

  int tid  = threadIdx.x;
  int lane = tid & 63;
  int wave = tid >> 6;
  int wm = wave >> 2, wn = wave & 3;        // 2x4 wave grid: 128x64 per wave

  int l15  = lane & 15;
  int csel = (lane >> 4) ^ ((lane >> 1) & 3);

  int idx0 = tid, idx1 = 512 + tid;
  int sr0 = idx0 >> 2, scl0 = (idx0 & 3) ^ ((sr0 >> 1) & 3);
  int sr1 = idx1 >> 2, scl1 = (idx1 & 3) ^ ((sr1 >> 1) & 3);
  int ld0 = idx0 * 8, ld1 = idx1 * 8;
  const ushort_t* pA0 = A + (size_t)(bm * 256 + sr0) * D_IN + scl0 * 8;
  const ushort_t* pA1 = A + (size_t)(bm * 256 + sr1) * D_IN + scl1 * 8;
  const ushort_t* pB0 = B + (size_t)(bn * 256 + sr0) * D_IN + scl0 * 8;
  const ushort_t* pB1 = B + (size_t)(bn * 256 + sr1) * D_IN + scl1 * 8;

  f32x4 acc[8][4];
#pragma unroll
  for (int m = 0; m < 8; m++)
#pragma unroll
    for (int n = 0; n < 4; n++) acc[m][n] = (f32x4){0.f, 0.f, 0.f, 0.f};

  // prologue: stage tiles 0,1,2 (12 gloads)
  gload_lds16(pA0,      lds + ld0);         gload_lds16(pA1,      lds + ld1);
  gload_lds16(pB0,      lds + 8192 + ld0);  gload_lds16(pB1,      lds + 8192 + ld1);
  gload_lds16(pA0 + 32, lds + 16384 + ld0); gload_lds16(pA1 + 32, lds + 16384 + ld1);
  gload_lds16(pB0 + 32, lds + 24576 + ld0); gload_lds16(pB1 + 32, lds + 24576 + ld1);
  gload_lds16(pA0 + 64, lds + 32768 + ld0); gload_lds16(pA1 + 64, lds + 32768 + ld1);
  gload_lds16(pB0 + 64, lds + 40960 + ld0); gload_lds16(pB1 + 64, lds + 40960 + ld1);
  pA0 += 96; pA1 += 96; pB0 += 96; pB1 += 96;   // in-loop staging starts at tile 3
  asm volatile("s_waitcnt vmcnt(4)" ::: "memory");   // tiles 0,1 landed; tile 2 in flight
  asm volatile("s_barrier" ::: "memory");

  int ar = wm * 128 + l15;
  int br = wn * 64 + l15;

  bf16x8 bv[2][4], a03[2][4], a47[2][4];

  // prologue reads for tile 0 (set 0) + half1(0)
  {
    const bf16x8* A8 = (const bf16x8*)lds;
    const bf16x8* B8 = A8 + 1024;
    bv[0][0]  = B8[(br +  0) * 4 + csel];
    bv[0][1]  = B8[(br + 16) * 4 + csel];
    bv[0][2]  = B8[(br + 32) * 4 + csel];
    bv[0][3]  = B8[(br + 48) * 4 + csel];
    a03[0][0] = A8[(ar +  0) * 4 + csel];
    a03[0][1] = A8[(ar + 16) * 4 + csel];
    a03[0][2] = A8[(ar + 32) * 4 + csel];
    a03[0][3] = A8[(ar + 48) * 4 + csel];
    __builtin_amdgcn_sched_barrier(0);
    a47[0][0] = A8[(ar +  64) * 4 + csel];
    a47[0][1] = A8[(ar +  80) * 4 + csel];
    a47[0][2] = A8[(ar +  96) * 4 + csel];
    a47[0][3] = A8[(ar + 112) * 4 + csel];
    __builtin_amdgcn_sched_barrier(0);
    asm volatile("s_waitcnt lgkmcnt(4)" ::: "memory");
    __builtin_amdgcn_sched_barrier(0);
    __builtin_amdgcn_s_setprio(1);
    MF16(a03[0], bv[0], 0)
    __builtin_amdgcn_s_setprio(0);
    __builtin_amdgcn_sched_barrier(0);
  }

  // bodies 0..126 (each computes half2(T) + half1(T+1))
  for (int tt = 0; tt < 63; tt++) {
    int t0 = tt * 2;
    GBODY(t0, 0, 1)
    GBODY(t0 + 1, 1, 0)
  }
  GBODY(126, 0, 1)

  // tail: half2(127)
  asm volatile("s_waitcnt lgkmcnt(0)" ::: "memory");
  __builtin_amdgcn_sched_barrier(0);
  __builtin_amdgcn_s_setprio(1);
  MF16(a47[1], bv[1], 4)
  __builtin_amdgcn_s_setprio(0);

  int orow0 = bm * 256 + wm * 128 + (lane >> 4) * 4;
  int ocol0 = bn * 256 + wn * 64 + l15;
#pragma unroll
  for (int n = 0; n < 4; n++) {
    float bb = bias[ocol0 + n * 16];
#pragma unroll
    for (int m = 0; m < 8; m++) {
#pragma unroll
      for (int r = 0; r < 4; r++) {
        C[(size_t)(orow0 + m * 16 + r) * D_OUT + ocol0 + n * 16] = acc[m][n][r] + bb;
      }
    }
  }
}

// ---------- launch ----------
extern "C" void kernel_launch(void* const* d_in, const int* in_sizes, int n_in,
                              void* d_out, int out_size, void* d_ws, size_t ws_size,
                              hipStream_t stream) {
  const float* x = (const float*)d_in[0];
  const float* w = (const float*)d_in[1];
  const float* bias = (const float*)d_in[2];
  float* out = (float*)d_out;

  char* ws = (char*)d_ws;
  uint32* hist1 = (uint32*)ws;                       // 2048 bins @ 0
  uint32* hs1   = (uint32*)(ws + 8192);              // 1024 bins
  uint32* hs2   = (uint32*)(ws + 12288);             // 1024 bins
  uint32* cnt   = (uint32*)(ws + 16384);             // 1 word
  ushort_t* Xb  = (ushort_t*)(ws + 65536);
  ushort_t* Wb  = (ushort_t*)(ws + 65536 + (size_t)NW * 2);
  uint2*   cand = (uint2*)(ws + 65536 + (size_t)NW * 4);

  hipMemsetAsync(d_ws, 0, 16448, stream);

  k1_hist1_convx<<<3072, 256, 0, stream>>>((const uint4*)w, hist1, (const float4*)x, (uint4*)Xb);
  k2_decide<<<512, 256, 0, stream>>>((const float4*)w, hist1, (uint4*)Wb, cand, cnt, hs1);
  s2_hist<<<128, 256, 0, stream>>>(cand, cnt, hist1, hs1, hs2);
  k5_fixup<<<256, 256, 0, stream>>>(cand, cnt, hist1, hs1, hs2, Wb);

  gemm_bt<<<256, 512, 131072, stream>>>(Xb, Wb, bias, out);
}

// Round 12
// 210.652 us; speedup vs baseline: 1.1032x; 1.0166x over previous
//
#include <hip/hip_runtime.h>
#include <stdint.h>

#define D_IN   4096
#define D_OUT  4096
#define NTOK   4096
#define NW     (D_OUT * D_IN)          // 16777216
#define RANK1  15099493u               // floor(0.9f * (NW-1)) as jax computes in f32
#define CAP    1500000                 // candidate list capacity (expected ~700K)

typedef unsigned int  uint32;
typedef unsigned short ushort_t;
typedef float  f32x4  __attribute__((ext_vector_type(4)));
typedef __bf16 bf16x8 __attribute__((ext_vector_type(8)));

// ---------- helpers ----------
__device__ __forceinline__ uint32 rne_bf16(float f) {
  uint32 u = __float_as_uint(f);
  return (u + 0x7FFFu + ((u >> 16) & 1u)) >> 16;
}

__device__ __forceinline__ void gload_lds16(const void* g, void* l) {
  __builtin_amdgcn_global_load_lds((__attribute__((address_space(1))) void*)(g),
                                   (__attribute__((address_space(3))) void*)(l), 16, 0, 0);
}

// block-redundant select: find bin containing `rank` in NB-bin global histogram.
template <int NB>
__device__ __forceinline__ void dsel(const uint32* __restrict__ h, uint32 rank,
                                     uint32* res, uint32* wtot) {
  constexpr int PER = NB >> 8;
  int tid = threadIdx.x;
  int lane = tid & 63, wid = tid >> 6;
  uint32 loc[PER];
  uint32 s = 0;
  int base = tid * PER;
#pragma unroll
  for (int i = 0; i < PER; i++) { loc[i] = h[base + i]; s += loc[i]; }
  uint32 v = s;
  for (int d = 1; d < 64; d <<= 1) { uint32 o = __shfl_up(v, (unsigned)d); if (lane >= d) v += o; }
  if (lane == 63) wtot[wid] = v;
  __syncthreads();
  uint32 woff = 0;
  for (int w = 0; w < wid; w++) woff += wtot[w];
  uint32 incl = v + woff, excl = incl - s;
  if (rank >= excl && rank < incl) {
    uint32 c = excl;
#pragma unroll
    for (int i = 0; i < PER; i++) {
      if (rank < c + loc[i]) { res[0] = (uint32)(base + i); res[1] = rank - c; break; }
      c += loc[i];
    }
  }
  __syncthreads();
}

// ---------- K1: hist pass 1 over |W| bits (pure; convx moved to K2) ----------
__global__ void k1_hist1(const uint4* __restrict__ wb, uint32* __restrict__ hist) {
  __shared__ uint32 lh[4][2048];
  for (int i = threadIdx.x; i < 8192; i += 256) ((uint32*)lh)[i] = 0;
  __syncthreads();
  int wid = threadIdx.x >> 6;
  int idx = blockIdx.x * 256 + threadIdx.x;
  for (int i = idx; i < NW / 4; i += 2048 * 256) {
    uint4 v = wb[i];
    atomicAdd(&lh[wid][(v.x & 0x7FFFFFFFu) >> 20], 1u);
    atomicAdd(&lh[wid][(v.y & 0x7FFFFFFFu) >> 20], 1u);
    atomicAdd(&lh[wid][(v.z & 0x7FFFFFFFu) >> 20], 1u);
    atomicAdd(&lh[wid][(v.w & 0x7FFFFFFFu) >> 20], 1u);
  }
  __syncthreads();
  for (int i = threadIdx.x; i < 2048; i += 256) {
    uint32 c = lh[0][i] + lh[1][i] + lh[2][i] + lh[3][i];
    if (c) atomicAdd(&hist[i], c);
  }
}

// ---------- K2: decide/convert W + compact candidates + fused s1 hist (blocks 0..511)
//              convert_x (blocks 512..1535) -- fills CUs idle during decide ----------
__global__ void k2_decide_convx(const float4* __restrict__ w, const uint32* __restrict__ hist1,
                                uint4* __restrict__ out, uint2* __restrict__ cand,
                                uint32* __restrict__ cnt, uint32* __restrict__ hs1,
                                const float4* __restrict__ x, uint4* __restrict__ xout) {
  if (blockIdx.x >= 512) {
    int i = (blockIdx.x - 512) * 256 + threadIdx.x;
    for (; i < NW / 8; i += 1024 * 256) {
      float4 a = x[2 * i], b = x[2 * i + 1];
      uint4 o;
      o.x = rne_bf16(a.x) | (rne_bf16(a.y) << 16);
      o.y = rne_bf16(a.z) | (rne_bf16(a.w) << 16);
      o.z = rne_bf16(b.x) | (rne_bf16(b.y) << 16);
      o.w = rne_bf16(b.z) | (rne_bf16(b.w) << 16);
      xout[i] = o;
    }
    return;
  }
  __shared__ uint32 res1[2], wt[4];
  __shared__ uint32 lcnt, lbase;
  __shared__ uint2 lbuf[3072];
  __shared__ uint32 lch[1024];
  for (int i = threadIdx.x; i < 1024; i += 256) lch[i] = 0;
  if (threadIdx.x == 0) lcnt = 0;
  dsel<2048>(hist1, RANK1, res1, wt);          // internal syncthreads orders the zeroing
  uint32 bstar = res1[0];
  int i = blockIdx.x * 256 + threadIdx.x;
  for (; i < NW / 8; i += 512 * 256) {
    float4 a = w[2 * i], b = w[2 * i + 1];
    float f[8] = {a.x, a.y, a.z, a.w, b.x, b.y, b.z, b.w};
    uint32 h[8];
#pragma unroll
    for (int j = 0; j < 8; j++) {
      uint32 bits = __float_as_uint(f[j]);
      uint32 bin = (bits & 0x7FFFFFFFu) >> 20;
      h[j] = (bin > bstar) ? rne_bf16(f[j]) : 0u;
      if (bin == bstar) {
        uint32 p = atomicAdd(&lcnt, 1u);
        if (p < 3072) {
          lbuf[p] = make_uint2((uint32)(8 * i + j), bits);
          atomicAdd(&lch[(bits >> 10) & 1023u], 1u);
        }
      }
    }
    uint4 o;
    o.x = h[0] | (h[1] << 16);
    o.y = h[2] | (h[3] << 16);
    o.z = h[4] | (h[5] << 16);
    o.w = h[6] | (h[7] << 16);
    out[i] = o;
  }
  __syncthreads();
  uint32 nstore = lcnt < 3072u ? lcnt : 3072u;
  if (threadIdx.x == 0) lbase = atomicAdd(cnt, nstore);
  __syncthreads();
  for (uint32 p = threadIdx.x; p < nstore; p += 256) {
    uint32 g = lbase + p;
    if (g < CAP) cand[g] = lbuf[p];
  }
  for (int ii = threadIdx.x; ii < 1024; ii += 256) if (lch[ii]) atomicAdd(&hs1[ii], lch[ii]);
}

// ---------- S2: filter on bits[19:10], hist bits [9:0] ----------
__global__ void s2_hist(const uint2* __restrict__ cand, const uint32* __restrict__ cnt,
                        const uint32* __restrict__ hist1, const uint32* __restrict__ hs1,
                        uint32* __restrict__ hs2) {
  __shared__ uint32 lh[1024];
  __shared__ uint32 res1[2], res2[2], wt[4];
  for (int i = threadIdx.x; i < 1024; i += 256) lh[i] = 0;
  dsel<2048>(hist1, RANK1, res1, wt);
  dsel<1024>(hs1, res1[1], res2, wt);
  uint32 b2 = res2[0];
  uint32 n = *cnt; if (n > CAP) n = CAP;
  for (uint32 i = blockIdx.x * 256 + threadIdx.x; i < n; i += gridDim.x * 256) {
    uint32 mag = cand[i].y & 0x7FFFFFFFu;
    if (((mag >> 10) & 1023u) == b2) atomicAdd(&lh[mag & 1023u], 1u);
  }
  __syncthreads();
  for (int i = threadIdx.x; i < 1024; i += 256) if (lh[i]) atomicAdd(&hs2[i], lh[i]);
}

// ---------- K5: final threshold, fix up kept candidates ----------
__global__ void k5_fixup(const uint2* __restrict__ cand, const uint32* __restrict__ cnt,
                         const uint32* __restrict__ hist1, const uint32* __restrict__ hs1,
                         const uint32* __restrict__ hs2, ushort_t* __restrict__ wb) {
  __shared__ uint32 res1[2], res2[2], res3[2], wt[4];
  dsel<2048>(hist1, RANK1, res1, wt);
  dsel<1024>(hs1, res1[1], res2, wt);
  dsel<1024>(hs2, res2[1], res3, wt);
  uint32 thr_mag = (res1[0] << 20) | (res2[0] << 10) | res3[0];
  uint32 n = *cnt; if (n > CAP) n = CAP;
  for (uint32 i = blockIdx.x * 256 + threadIdx.x; i < n; i += gridDim.x * 256) {
    uint2 c = cand[i];
    uint32 mag = c.y & 0x7FFFFFFFu;
    if (mag > thr_mag) wb[c.x] = (ushort_t)rne_bf16(__uint_as_float(c.y));
  }
}

// ---------- GEMM: C[M,N] = Xb[M,K] * Wb[N,K]^T + bias ----------
// FROZEN R5 structure (103.2-105.0 us, MfmaUtil ~58%, reproduced 4x): 256x256
// tile, BK=32, 8 waves (2x4), QUAD-buffered LDS (128KB), stage 3-ahead,
// software-pipelined frag reads; each MFMA burst runs with 4-8 ds_reads in
// flight for the NEXT half-tile. One barrier + one counted vmcnt(4) per K-tile.
#define TILES 128

#define MF16(AF, BF, MO)                                                                          \
  acc[(MO)+0][0] = __builtin_amdgcn_mfma_f32_16x16x32_bf16(AF[0], BF[0], acc[(MO)+0][0], 0,0,0);  \
  acc[(MO)+0][1] = __builtin_amdgcn_mfma_f32_16x16x32_bf16(AF[0], BF[1], acc[(MO)+0][1], 0,0,0);  \
  acc[(MO)+0][2] = __builtin_amdgcn_mfma_f32_16x16x32_bf16(AF[0], BF[2], acc[(MO)+0][2], 0,0,0);  \
  acc[(MO)+0][3] = __builtin_amdgcn_mfma_f32_16x16x32_bf16(AF[0], BF[3], acc[(MO)+0][3], 0,0,0);  \
  acc[(MO)+1][0] = __builtin_amdgcn_mfma_f32_16x16x32_bf16(AF[1], BF[0], acc[(MO)+1][0], 0,0,0);  \
  acc[(MO)+1][1] = __builtin_amdgcn_mfma_f32_16x16x32_bf16(AF[1], BF[1], acc[(MO)+1][1], 0,0,0);  \
  acc[(MO)+1][2] = __builtin_amdgcn_mfma_f32_16x16x32_bf16(AF[1], BF[2], acc[(MO)+1][2], 0,0,0);  \
  acc[(MO)+1][3] = __builtin_amdgcn_mfma_f32_16x16x32_bf16(AF[1], BF[3], acc[(MO)+1][3], 0,0,0);  \
  acc[(MO)+2][0] = __builtin_amdgcn_mfma_f32_16x16x32_bf16(AF[2], BF[0], acc[(MO)+2][0], 0,0,0);  \
  acc[(MO)+2][1] = __builtin_amdgcn_mfma_f32_16x16x32_bf16(AF[2], BF[1], acc[(MO)+2][1], 0,0,0);  \
  acc[(MO)+2][2] = __builtin_amdgcn_mfma_f32_16x16x32_bf16(AF[2], BF[2], acc[(MO)+2][2], 0,0,0);  \
  acc[(MO)+2][3] = __builtin_amdgcn_mfma_f32_16x16x32_bf16(AF[2], BF[3], acc[(MO)+2][3], 0,0,0);  \
  acc[(MO)+3][0] = __builtin_amdgcn_mfma_f32_16x16x32_bf16(AF[3], BF[0], acc[(MO)+3][0], 0,0,0);  \
  acc[(MO)+3][1] = __builtin_amdgcn_mfma_f32_16x16x32_bf16(AF[3], BF[1], acc[(MO)+3][1], 0,0,0);  \
  acc[(MO)+3][2] = __builtin_amdgcn_mfma_f32_16x16x32_bf16(AF[3], BF[2], acc[(MO)+3][2], 0,0,0);  \
  acc[(MO)+3][3] = __builtin_amdgcn_mfma_f32_16x16x32_bf16(AF[3], BF[3], acc[(MO)+3][3], 0,0,0);

// Body T: computes half2(T) then half1(T+1). S = T&1, SN = (T+1)&1 (literals).
#define GBODY(T, S, SN)                                                        \
  {                                                                            \
    const bf16x8* A8n = (const bf16x8*)(lds + (((T) + 1) & 3) * 16384);        \
    const bf16x8* B8n = A8n + 1024;                                            \
    bv[SN][0]  = B8n[(br +  0) * 4 + csel];                                    \
    bv[SN][1]  = B8n[(br + 16) * 4 + csel];                                    \
    bv[SN][2]  = B8n[(br + 32) * 4 + csel];                                    \
    bv[SN][3]  = B8n[(br + 48) * 4 + csel];                                    \
    a03[SN][0] = A8n[(ar +  0) * 4 + csel];                                    \
    a03[SN][1] = A8n[(ar + 16) * 4 + csel];                                    \
    a03[SN][2] = A8n[(ar + 32) * 4 + csel];                                    \
    a03[SN][3] = A8n[(ar + 48) * 4 + csel];                                    \
    __builtin_amdgcn_sched_barrier(0);                                         \
    ushort_t* sb = lds + (((T) + 3) & 3) * 16384;                              \
    gload_lds16(pA0, sb + ld0);                                                \
    gload_lds16(pA1, sb + ld1);                                                \
    gload_lds16(pB0, sb + 8192 + ld0);                                         \
    gload_lds16(pB1, sb + 8192 + ld1);                                         \
    __builtin_amdgcn_sched_barrier(0);                                         \
    asm volatile("s_waitcnt lgkmcnt(8)" ::: "memory");                         \
    __builtin_amdgcn_sched_barrier(0);                                         \
    __builtin_amdgcn_s_setprio(1);                                             \
    MF16(a47[S], bv[S], 4)                                                     \
    __builtin_amdgcn_s_setprio(0);                                             \
    __builtin_amdgcn_sched_barrier(0);                                         \
    a47[SN][0] = A8n[(ar +  64) * 4 + csel];                                   \
    a47[SN][1] = A8n[(ar +  80) * 4 + csel];                                   \
    a47[SN][2] = A8n[(ar +  96) * 4 + csel];                                   \
    a47[SN][3] = A8n[(ar + 112) * 4 + csel];                                   \
    __builtin_amdgcn_sched_barrier(0);                                         \
    asm volatile("s_waitcnt lgkmcnt(4)" ::: "memory");                         \
    asm volatile("s_waitcnt vmcnt(4)" ::: "memory");                           \
    asm volatile("s_barrier" ::: "memory");                                    \
    __builtin_amdgcn_sched_barrier(0);                                         \
    __builtin_amdgcn_s_setprio(1);                                             \
    MF16(a03[SN], bv[SN], 0)                                                   \
    __builtin_amdgcn_s_setprio(0);                                             \
    __builtin_amdgcn_sched_barrier(0);                                         \
    if ((T) < TILES - 4) { pA0 += 32; pA1 += 32; pB0 += 32; pB1 += 32; }       \
  }

__global__ __launch_bounds__(512, 2) void gemm_bt(const ushort_t* __restrict__ A,
                                                  const ushort_t* __restrict__ B,
                                                  const float* __restrict__ bias,
                                                  float* __restrict__ C) {
  extern __shared__ ushort_t lds[];   // 4 bufs x 32KB = 128KB

  int bid = blockIdx.x;                     // 256 blocks
  int swz = (bid & 7) * 32 + (bid >> 3);    // bijective XCD swizzle
  int bm = swz >> 4;
  int bn = swz & 15;

  int tid  = threadIdx.x;
  int lane = tid & 63;
  int wave = tid >> 6;
  int wm = wave >> 2, wn = wave & 3;        // 2x4 wave grid: 128x64 per wave

  int l15  = lane & 15;
  int csel = (lane >> 4) ^ ((lane >> 1) & 3);

  int idx0 = tid, idx1 = 512 + tid;
  int sr0 = idx0 >> 2, scl0 = (idx0 & 3) ^ ((sr0 >> 1) & 3);
  int sr1 = idx1 >> 2, scl1 = (idx1 & 3) ^ ((sr1 >> 1) & 3);
  int ld0 = idx0 * 8, ld1 = idx1 * 8;
  const ushort_t* pA0 = A + (size_t)(bm * 256 + sr0) * D_IN + scl0 * 8;
  const ushort_t* pA1 = A + (size_t)(bm * 256 + sr1) * D_IN + scl1 * 8;
  const ushort_t* pB0 = B + (size_t)(bn * 256 + sr0) * D_IN + scl0 * 8;
  const ushort_t* pB1 = B + (size_t)(bn * 256 + sr1) * D_IN + scl1 * 8;

  f32x4 acc[8][4];
#pragma unroll
  for (int m = 0; m < 8; m++)
#pragma unroll
    for (int n = 0; n < 4; n++) acc[m][n] = (f32x4){0.f, 0.f, 0.f, 0.f};

  // prologue: stage tiles 0,1,2 (12 gloads)
  gload_lds16(pA0,      lds + ld0);         gload_lds16(pA1,      lds + ld1);
  gload_lds16(pB0,      lds + 8192 + ld0);  gload_lds16(pB1,      lds + 8192 + ld1);
  gload_lds16(pA0 + 32, lds + 16384 + ld0); gload_lds16(pA1 + 32, lds + 16384 + ld1);
  gload_lds16(pB0 + 32, lds + 24576 + ld0); gload_lds16(pB1 + 32, lds + 24576 + ld1);
  gload_lds16(pA0 + 64, lds + 32768 + ld0); gload_lds16(pA1 + 64, lds + 32768 + ld1);
  gload_lds16(pB0 + 64, lds + 40960 + ld0); gload_lds16(pB1 + 64, lds + 40960 + ld1);
  pA0 += 96; pA1 += 96; pB0 += 96; pB1 += 96;   // in-loop staging starts at tile 3
  asm volatile("s_waitcnt vmcnt(4)" ::: "memory");   // tiles 0,1 landed; tile 2 in flight
  asm volatile("s_barrier" ::: "memory");

  int ar = wm * 128 + l15;
  int br = wn * 64 + l15;

  bf16x8 bv[2][4], a03[2][4], a47[2][4];

  // prologue reads for tile 0 (set 0) + half1(0)
  {
    const bf16x8* A8 = (const bf16x8*)lds;
    const bf16x8* B8 = A8 + 1024;
    bv[0][0]  = B8[(br +  0) * 4 + csel];
    bv[0][1]  = B8[(br + 16) * 4 + csel];
    bv[0][2]  = B8[(br + 32) * 4 + csel];
    bv[0][3]  = B8[(br + 48) * 4 + csel];
    a03[0][0] = A8[(ar +  0) * 4 + csel];
    a03[0][1] = A8[(ar + 16) * 4 + csel];
    a03[0][2] = A8[(ar + 32) * 4 + csel];
    a03[0][3] = A8[(ar + 48) * 4 + csel];
    __builtin_amdgcn_sched_barrier(0);
    a47[0][0] = A8[(ar +  64) * 4 + csel];
    a47[0][1] = A8[(ar +  80) * 4 + csel];
    a47[0][2] = A8[(ar +  96) * 4 + csel];
    a47[0][3] = A8[(ar + 112) * 4 + csel];
    __builtin_amdgcn_sched_barrier(0);
    asm volatile("s_waitcnt lgkmcnt(4)" ::: "memory");
    __builtin_amdgcn_sched_barrier(0);
    __builtin_amdgcn_s_setprio(1);
    MF16(a03[0], bv[0], 0)
    __builtin_amdgcn_s_setprio(0);
    __builtin_amdgcn_sched_barrier(0);
  }

  // bodies 0..126 (each computes half2(T) + half1(T+1))
  for (int tt = 0; tt < 63; tt++) {
    int t0 = tt * 2;
    GBODY(t0, 0, 1)
    GBODY(t0 + 1, 1, 0)
  }
  GBODY(126, 0, 1)

  // tail: half2(127)
  asm volatile("s_waitcnt lgkmcnt(0)" ::: "memory");
  __builtin_amdgcn_sched_barrier(0);
  __builtin_amdgcn_s_setprio(1);
  MF16(a47[1], bv[1], 4)
  __builtin_amdgcn_s_setprio(0);

  int orow0 = bm * 256 + wm * 128 + (lane >> 4) * 4;
  int ocol0 = bn * 256 + wn * 64 + l15;
#pragma unroll
  for (int n = 0; n < 4; n++) {
    float bb = bias[ocol0 + n * 16];
#pragma unroll
    for (int m = 0; m < 8; m++) {
#pragma unroll
      for (int r = 0; r < 4; r++) {
        C[(size_t)(orow0 + m * 16 + r) * D_OUT + ocol0 + n * 16] = acc[m][n][r] + bb;
      }
    }
  }
}

// ---------- launch ----------
extern "C" void kernel_launch(void* const* d_in, const int* in_sizes, int n_in,
                              void* d_out, int out_size, void* d_ws, size_t ws_size,
                              hipStream_t stream) {
  const float* x = (const float*)d_in[0];
  const float* w = (const float*)d_in[1];
  const float* bias = (const float*)d_in[2];
  float* out = (float*)d_out;

  char* ws = (char*)d_ws;
  uint32* hist1 = (uint32*)ws;                       // 2048 bins @ 0
  uint32* hs1   = (uint32*)(ws + 8192);              // 1024 bins
  uint32* hs2   = (uint32*)(ws + 12288);             // 1024 bins
  uint32* cnt   = (uint32*)(ws + 16384);             // 1 word
  ushort_t* Xb  = (ushort_t*)(ws + 65536);
  ushort_t* Wb  = (ushort_t*)(ws + 65536 + (size_t)NW * 2);
  uint2*   cand = (uint2*)(ws + 65536 + (size_t)NW * 4);

  hipMemsetAsync(d_ws, 0, 16448, stream);

  k1_hist1<<<2048, 256, 0, stream>>>((const uint4*)w, hist1);
  k2_decide_convx<<<1536, 256, 0, stream>>>((const float4*)w, hist1, (uint4*)Wb, cand, cnt, hs1,
                                            (const float4*)x, (uint4*)Xb);
  s2_hist<<<128, 256, 0, stream>>>(cand, cnt, hist1, hs1, hs2);
  k5_fixup<<<256, 256, 0, stream>>>(cand, cnt, hist1, hs1, hs2, Wb);

  gemm_bt<<<256, 512, 131072, stream>>>(Xb, Wb, bias, out);
}

// Round 13
// 207.089 us; speedup vs baseline: 1.1221x; 1.0172x over previous
//
#include <hip/hip_runtime.h>
#include <stdint.h>

#define D_IN   4096
#define D_OUT  4096
#define NTOK   4096
#define NW     (D_OUT * D_IN)          // 16777216
#define RANK1  15099493u               // floor(0.9f * (NW-1)) as jax computes in f32
#define CAP    1500000                 // candidate list capacity (expected ~700K)

typedef unsigned int  uint32;
typedef unsigned short ushort_t;
typedef float  f32x4  __attribute__((ext_vector_type(4)));
typedef __bf16 bf16x8 __attribute__((ext_vector_type(8)));

// ---------- helpers ----------
__device__ __forceinline__ uint32 rne_bf16(float f) {
  uint32 u = __float_as_uint(f);
  return (u + 0x7FFFu + ((u >> 16) & 1u)) >> 16;
}

__device__ __forceinline__ void gload_lds16(const void* g, void* l) {
  __builtin_amdgcn_global_load_lds((__attribute__((address_space(1))) void*)(g),
                                   (__attribute__((address_space(3))) void*)(l), 16, 0, 0);
}

// block-redundant select: find bin containing `rank` in NB-bin global histogram.
template <int NB>
__device__ __forceinline__ void dsel(const uint32* __restrict__ h, uint32 rank,
                                     uint32* res, uint32* wtot) {
  constexpr int PER = NB >> 8;
  int tid = threadIdx.x;
  int lane = tid & 63, wid = tid >> 6;
  uint32 loc[PER];
  uint32 s = 0;
  int base = tid * PER;
#pragma unroll
  for (int i = 0; i < PER; i++) { loc[i] = h[base + i]; s += loc[i]; }
  uint32 v = s;
  for (int d = 1; d < 64; d <<= 1) { uint32 o = __shfl_up(v, (unsigned)d); if (lane >= d) v += o; }
  if (lane == 63) wtot[wid] = v;
  __syncthreads();
  uint32 woff = 0;
  for (int w = 0; w < wid; w++) woff += wtot[w];
  uint32 incl = v + woff, excl = incl - s;
  if (rank >= excl && rank < incl) {
    uint32 c = excl;
#pragma unroll
    for (int i = 0; i < PER; i++) {
      if (rank < c + loc[i]) { res[0] = (uint32)(base + i); res[1] = rank - c; break; }
      c += loc[i];
    }
  }
  __syncthreads();
}

// ---------- K1: hist pass 1 over |W| bits, 2x unrolled for MLP/atomic overlap ----------
__global__ void k1_hist1(const uint4* __restrict__ wb, uint32* __restrict__ hist) {
  __shared__ uint32 lh[4][2048];
  for (int i = threadIdx.x; i < 8192; i += 256) ((uint32*)lh)[i] = 0;
  __syncthreads();
  int wid = threadIdx.x >> 6;
  int idx = blockIdx.x * 256 + threadIdx.x;
  // NW/4 = 4194304 elements of uint4; stride 2048*256 = 524288; exactly 8 iters -> 4 unrolled x2
  for (int i = idx; i < NW / 4; i += 2 * 2048 * 256) {
    uint4 v0 = wb[i];
    uint4 v1 = wb[i + 2048 * 256];
    atomicAdd(&lh[wid][(v0.x & 0x7FFFFFFFu) >> 20], 1u);
    atomicAdd(&lh[wid][(v0.y & 0x7FFFFFFFu) >> 20], 1u);
    atomicAdd(&lh[wid][(v0.z & 0x7FFFFFFFu) >> 20], 1u);
    atomicAdd(&lh[wid][(v0.w & 0x7FFFFFFFu) >> 20], 1u);
    atomicAdd(&lh[wid][(v1.x & 0x7FFFFFFFu) >> 20], 1u);
    atomicAdd(&lh[wid][(v1.y & 0x7FFFFFFFu) >> 20], 1u);
    atomicAdd(&lh[wid][(v1.z & 0x7FFFFFFFu) >> 20], 1u);
    atomicAdd(&lh[wid][(v1.w & 0x7FFFFFFFu) >> 20], 1u);
  }
  __syncthreads();
  for (int i = threadIdx.x; i < 2048; i += 256) {
    uint32 c = lh[0][i] + lh[1][i] + lh[2][i] + lh[3][i];
    if (c) atomicAdd(&hist[i], c);
  }
}

// ---------- K2: decide/convert W + compact candidates + fused s1 hist (blocks 0..511)
//              convert_x (blocks 512..1535) -- fills CUs idle during decide ----------
__global__ void k2_decide_convx(const float4* __restrict__ w, const uint32* __restrict__ hist1,
                                uint4* __restrict__ out, uint2* __restrict__ cand,
                                uint32* __restrict__ cnt, uint32* __restrict__ hs1,
                                const float4* __restrict__ x, uint4* __restrict__ xout) {
  if (blockIdx.x >= 512) {
    int i = (blockIdx.x - 512) * 256 + threadIdx.x;
    for (; i < NW / 8; i += 1024 * 256) {
      float4 a = x[2 * i], b = x[2 * i + 1];
      uint4 o;
      o.x = rne_bf16(a.x) | (rne_bf16(a.y) << 16);
      o.y = rne_bf16(a.z) | (rne_bf16(a.w) << 16);
      o.z = rne_bf16(b.x) | (rne_bf16(b.y) << 16);
      o.w = rne_bf16(b.z) | (rne_bf16(b.w) << 16);
      xout[i] = o;
    }
    return;
  }
  __shared__ uint32 res1[2], wt[4];
  __shared__ uint32 lcnt, lbase;
  __shared__ uint2 lbuf[3072];
  __shared__ uint32 lch[1024];
  for (int i = threadIdx.x; i < 1024; i += 256) lch[i] = 0;
  if (threadIdx.x == 0) lcnt = 0;
  dsel<2048>(hist1, RANK1, res1, wt);          // internal syncthreads orders the zeroing
  uint32 bstar = res1[0];
  int i = blockIdx.x * 256 + threadIdx.x;
  for (; i < NW / 8; i += 512 * 256) {
    float4 a = w[2 * i], b = w[2 * i + 1];
    float f[8] = {a.x, a.y, a.z, a.w, b.x, b.y, b.z, b.w};
    uint32 h[8];
#pragma unroll
    for (int j = 0; j < 8; j++) {
      uint32 bits = __float_as_uint(f[j]);
      uint32 bin = (bits & 0x7FFFFFFFu) >> 20;
      h[j] = (bin > bstar) ? rne_bf16(f[j]) : 0u;
      if (bin == bstar) {
        uint32 p = atomicAdd(&lcnt, 1u);
        if (p < 3072) {
          lbuf[p] = make_uint2((uint32)(8 * i + j), bits);
          atomicAdd(&lch[(bits >> 10) & 1023u], 1u);
        }
      }
    }
    uint4 o;
    o.x = h[0] | (h[1] << 16);
    o.y = h[2] | (h[3] << 16);
    o.z = h[4] | (h[5] << 16);
    o.w = h[6] | (h[7] << 16);
    out[i] = o;
  }
  __syncthreads();
  uint32 nstore = lcnt < 3072u ? lcnt : 3072u;
  if (threadIdx.x == 0) lbase = atomicAdd(cnt, nstore);
  __syncthreads();
  for (uint32 p = threadIdx.x; p < nstore; p += 256) {
    uint32 g = lbase + p;
    if (g < CAP) cand[g] = lbuf[p];
  }
  for (int ii = threadIdx.x; ii < 1024; ii += 256) if (lch[ii]) atomicAdd(&hs1[ii], lch[ii]);
}

// ---------- S2: filter on bits[19:10], hist bits [9:0] ----------
__global__ void s2_hist(const uint2* __restrict__ cand, const uint32* __restrict__ cnt,
                        const uint32* __restrict__ hist1, const uint32* __restrict__ hs1,
                        uint32* __restrict__ hs2) {
  __shared__ uint32 lh[1024];
  __shared__ uint32 res1[2], res2[2], wt[4];
  for (int i = threadIdx.x; i < 1024; i += 256) lh[i] = 0;
  dsel<2048>(hist1, RANK1, res1, wt);
  dsel<1024>(hs1, res1[1], res2, wt);
  uint32 b2 = res2[0];
  uint32 n = *cnt; if (n > CAP) n = CAP;
  for (uint32 i = blockIdx.x * 256 + threadIdx.x; i < n; i += gridDim.x * 256) {
    uint32 mag = cand[i].y & 0x7FFFFFFFu;
    if (((mag >> 10) & 1023u) == b2) atomicAdd(&lh[mag & 1023u], 1u);
  }
  __syncthreads();
  for (int i = threadIdx.x; i < 1024; i += 256) if (lh[i]) atomicAdd(&hs2[i], lh[i]);
}

// ---------- K5: final threshold, fix up kept candidates ----------
__global__ void k5_fixup(const uint2* __restrict__ cand, const uint32* __restrict__ cnt,
                         const uint32* __restrict__ hist1, const uint32* __restrict__ hs1,
                         const uint32* __restrict__ hs2, ushort_t* __restrict__ wb) {
  __shared__ uint32 res1[2], res2[2], res3[2], wt[4];
  dsel<2048>(hist1, RANK1, res1, wt);
  dsel<1024>(hs1, res1[1], res2, wt);
  dsel<1024>(hs2, res2[1], res3, wt);
  uint32 thr_mag = (res1[0] << 20) | (res2[0] << 10) | res3[0];
  uint32 n = *cnt; if (n > CAP) n = CAP;
  for (uint32 i = blockIdx.x * 256 + threadIdx.x; i < n; i += gridDim.x * 256) {
    uint2 c = cand[i];
    uint32 mag = c.y & 0x7FFFFFFFu;
    if (mag > thr_mag) wb[c.x] = (ushort_t)rne_bf16(__uint_as_float(c.y));
  }
}

// ---------- GEMM: C[M,N] = Xb[M,K] * Wb[N,K]^T + bias ----------
// FROZEN R5 structure (103.2-106 us, MfmaUtil ~58%, reproduced 5x): 256x256
// tile, BK=32, 8 waves (2x4), QUAD-buffered LDS (128KB), stage 3-ahead,
// software-pipelined frag reads; each MFMA burst runs with 4-8 ds_reads in
// flight for the NEXT half-tile. One barrier + one counted vmcnt(4) per K-tile.
#define TILES 128

#define MF16(AF, BF, MO)                                                                          \
  acc[(MO)+0][0] = __builtin_amdgcn_mfma_f32_16x16x32_bf16(AF[0], BF[0], acc[(MO)+0][0], 0,0,0);  \
  acc[(MO)+0][1] = __builtin_amdgcn_mfma_f32_16x16x32_bf16(AF[0], BF[1], acc[(MO)+0][1], 0,0,0);  \
  acc[(MO)+0][2] = __builtin_amdgcn_mfma_f32_16x16x32_bf16(AF[0], BF[2], acc[(MO)+0][2], 0,0,0);  \
  acc[(MO)+0][3] = __builtin_amdgcn_mfma_f32_16x16x32_bf16(AF[0], BF[3], acc[(MO)+0][3], 0,0,0);  \
  acc[(MO)+1][0] = __builtin_amdgcn_mfma_f32_16x16x32_bf16(AF[1], BF[0], acc[(MO)+1][0], 0,0,0);  \
  acc[(MO)+1][1] = __builtin_amdgcn_mfma_f32_16x16x32_bf16(AF[1], BF[1], acc[(MO)+1][1], 0,0,0);  \
  acc[(MO)+1][2] = __builtin_amdgcn_mfma_f32_16x16x32_bf16(AF[1], BF[2], acc[(MO)+1][2], 0,0,0);  \
  acc[(MO)+1][3] = __builtin_amdgcn_mfma_f32_16x16x32_bf16(AF[1], BF[3], acc[(MO)+1][3], 0,0,0);  \
  acc[(MO)+2][0] = __builtin_amdgcn_mfma_f32_16x16x32_bf16(AF[2], BF[0], acc[(MO)+2][0], 0,0,0);  \
  acc[(MO)+2][1] = __builtin_amdgcn_mfma_f32_16x16x32_bf16(AF[2], BF[1], acc[(MO)+2][1], 0,0,0);  \
  acc[(MO)+2][2] = __builtin_amdgcn_mfma_f32_16x16x32_bf16(AF[2], BF[2], acc[(MO)+2][2], 0,0,0);  \
  acc[(MO)+2][3] = __builtin_amdgcn_mfma_f32_16x16x32_bf16(AF[2], BF[3], acc[(MO)+2][3], 0,0,0);  \
  acc[(MO)+3][0] = __builtin_amdgcn_mfma_f32_16x16x32_bf16(AF[3], BF[0], acc[(MO)+3][0], 0,0,0);  \
  acc[(MO)+3][1] = __builtin_amdgcn_mfma_f32_16x16x32_bf16(AF[3], BF[1], acc[(MO)+3][1], 0,0,0);  \
  acc[(MO)+3][2] = __builtin_amdgcn_mfma_f32_16x16x32_bf16(AF[3], BF[2], acc[(MO)+3][2], 0,0,0);  \
  acc[(MO)+3][3] = __builtin_amdgcn_mfma_f32_16x16x32_bf16(AF[3], BF[3], acc[(MO)+3][3], 0,0,0);

// Body T: computes half2(T) then half1(T+1). S = T&1, SN = (T+1)&1 (literals).
#define GBODY(T, S, SN)                                                        \
  {                                                                            \
    const bf16x8* A8n = (const bf16x8*)(lds + (((T) + 1) & 3) * 16384);        \
    const bf16x8* B8n = A8n + 1024;                                            \
    bv[SN][0]  = B8n[(br +  0) * 4 + csel];                                    \
    bv[SN][1]  = B8n[(br + 16) * 4 + csel];                                    \
    bv[SN][2]  = B8n[(br + 32) * 4 + csel];                                    \
    bv[SN][3]  = B8n[(br + 48) * 4 + csel];                                    \
    a03[SN][0] = A8n[(ar +  0) * 4 + csel];                                    \
    a03[SN][1] = A8n[(ar + 16) * 4 + csel];                                    \
    a03[SN][2] = A8n[(ar + 32) * 4 + csel];                                    \
    a03[SN][3] = A8n[(ar + 48) * 4 + csel];                                    \
    __builtin_amdgcn_sched_barrier(0);                                         \
    ushort_t* sb = lds + (((T) + 3) & 3) * 16384;                              \
    gload_lds16(pA0, sb + ld0);                                                \
    gload_lds16(pA1, sb + ld1);                                                \
    gload_lds16(pB0, sb + 8192 + ld0);                                         \
    gload_lds16(pB1, sb + 8192 + ld1);                                         \
    __builtin_amdgcn_sched_barrier(0);                                         \
    asm volatile("s_waitcnt lgkmcnt(8)" ::: "memory");                         \
    __builtin_amdgcn_sched_barrier(0);                                         \
    __builtin_amdgcn_s_setprio(1);                                             \
    MF16(a47[S], bv[S], 4)                                                     \
    __builtin_amdgcn_s_setprio(0);                                             \
    __builtin_amdgcn_sched_barrier(0);                                         \
    a47[SN][0] = A8n[(ar +  64) * 4 + csel];                                   \
    a47[SN][1] = A8n[(ar +  80) * 4 + csel];                                   \
    a47[SN][2] = A8n[(ar +  96) * 4 + csel];                                   \
    a47[SN][3] = A8n[(ar + 112) * 4 + csel];                                   \
    __builtin_amdgcn_sched_barrier(0);                                         \
    asm volatile("s_waitcnt lgkmcnt(4)" ::: "memory");                         \
    asm volatile("s_waitcnt vmcnt(4)" ::: "memory");                           \
    asm volatile("s_barrier" ::: "memory");                                    \
    __builtin_amdgcn_sched_barrier(0);                                         \
    __builtin_amdgcn_s_setprio(1);                                             \
    MF16(a03[SN], bv[SN], 0)                                                   \
    __builtin_amdgcn_s_setprio(0);                                             \
    __builtin_amdgcn_sched_barrier(0);                                         \
    if ((T) < TILES - 4) { pA0 += 32; pA1 += 32; pB0 += 32; pB1 += 32; }       \
  }

__global__ __launch_bounds__(512, 2) void gemm_bt(const ushort_t* __restrict__ A,
                                                  const ushort_t* __restrict__ B,
                                                  const float* __restrict__ bias,
                                                  float* __restrict__ C) {
  extern __shared__ ushort_t lds[];   // 4 bufs x 32KB = 128KB

  int bid = blockIdx.x;                     // 256 blocks
  int swz = (bid & 7) * 32 + (bid >> 3);    // bijective XCD swizzle
  int bm = swz >> 4;
  int bn = swz & 15;

  int tid  = threadIdx.x;
  int lane = tid & 63;
  int wave = tid >> 6;
  int wm = wave >> 2, wn = wave & 3;        // 2x4 wave grid: 128x64 per wave

  int l15  = lane & 15;
  int csel = (lane >> 4) ^ ((lane >> 1) & 3);

  int idx0 = tid, idx1 = 512 + tid;
  int sr0 = idx0 >> 2, scl0 = (idx0 & 3) ^ ((sr0 >> 1) & 3);
  int sr1 = idx1 >> 2, scl1 = (idx1 & 3) ^ ((sr1 >> 1) & 3);
  int ld0 = idx0 * 8, ld1 = idx1 * 8;
  const ushort_t* pA0 = A + (size_t)(bm * 256 + sr0) * D_IN + scl0 * 8;
  const ushort_t* pA1 = A + (size_t)(bm * 256 + sr1) * D_IN + scl1 * 8;
  const ushort_t* pB0 = B + (size_t)(bn * 256 + sr0) * D_IN + scl0 * 8;
  const ushort_t* pB1 = B + (size_t)(bn * 256 + sr1) * D_IN + scl1 * 8;

  f32x4 acc[8][4];
#pragma unroll
  for (int m = 0; m < 8; m++)
#pragma unroll
    for (int n = 0; n < 4; n++) acc[m][n] = (f32x4){0.f, 0.f, 0.f, 0.f};

  // prologue: stage tiles 0,1,2 (12 gloads)
  gload_lds16(pA0,      lds + ld0);         gload_lds16(pA1,      lds + ld1);
  gload_lds16(pB0,      lds + 8192 + ld0);  gload_lds16(pB1,      lds + 8192 + ld1);
  gload_lds16(pA0 + 32, lds + 16384 + ld0); gload_lds16(pA1 + 32, lds + 16384 + ld1);
  gload_lds16(pB0 + 32, lds + 24576 + ld0); gload_lds16(pB1 + 32, lds + 24576 + ld1);
  gload_lds16(pA0 + 64, lds + 32768 + ld0); gload_lds16(pA1 + 64, lds + 32768 + ld1);
  gload_lds16(pB0 + 64, lds + 40960 + ld0); gload_lds16(pB1 + 64, lds + 40960 + ld1);
  pA0 += 96; pA1 += 96; pB0 += 96; pB1 += 96;   // in-loop staging starts at tile 3
  asm volatile("s_waitcnt vmcnt(4)" ::: "memory");   // tiles 0,1 landed; tile 2 in flight
  asm volatile("s_barrier" ::: "memory");

  int ar = wm * 128 + l15;
  int br = wn * 64 + l15;

  bf16x8 bv[2][4], a03[2][4], a47[2][4];

  // prologue reads for tile 0 (set 0) + half1(0)
  {
    const bf16x8* A8 = (const bf16x8*)lds;
    const bf16x8* B8 = A8 + 1024;
    bv[0][0]  = B8[(br +  0) * 4 + csel];
    bv[0][1]  = B8[(br + 16) * 4 + csel];
    bv[0][2]  = B8[(br + 32) * 4 + csel];
    bv[0][3]  = B8[(br + 48) * 4 + csel];
    a03[0][0] = A8[(ar +  0) * 4 + csel];
    a03[0][1] = A8[(ar + 16) * 4 + csel];
    a03[0][2] = A8[(ar + 32) * 4 + csel];
    a03[0][3] = A8[(ar + 48) * 4 + csel];
    __builtin_amdgcn_sched_barrier(0);
    a47[0][0] = A8[(ar +  64) * 4 + csel];
    a47[0][1] = A8[(ar +  80) * 4 + csel];
    a47[0][2] = A8[(ar +  96) * 4 + csel];
    a47[0][3] = A8[(ar + 112) * 4 + csel];
    __builtin_amdgcn_sched_barrier(0);
    asm volatile("s_waitcnt lgkmcnt(4)" ::: "memory");
    __builtin_amdgcn_sched_barrier(0);
    __builtin_amdgcn_s_setprio(1);
    MF16(a03[0], bv[0], 0)
    __builtin_amdgcn_s_setprio(0);
    __builtin_amdgcn_sched_barrier(0);
  }

  // bodies 0..126 (each computes half2(T) + half1(T+1))
  for (int tt = 0; tt < 63; tt++) {
    int t0 = tt * 2;
    GBODY(t0, 0, 1)
    GBODY(t0 + 1, 1, 0)
  }
  GBODY(126, 0, 1)

  // tail: half2(127)
  asm volatile("s_waitcnt lgkmcnt(0)" ::: "memory");
  __builtin_amdgcn_sched_barrier(0);
  __builtin_amdgcn_s_setprio(1);
  MF16(a47[1], bv[1], 4)
  __builtin_amdgcn_s_setprio(0);

  int orow0 = bm * 256 + wm * 128 + (lane >> 4) * 4;
  int ocol0 = bn * 256 + wn * 64 + l15;
#pragma unroll
  for (int n = 0; n < 4; n++) {
    float bb = bias[ocol0 + n * 16];
#pragma unroll
    for (int m = 0; m < 8; m++) {
#pragma unroll
      for (int r = 0; r < 4; r++) {
        C[(size_t)(orow0 + m * 16 + r) * D_OUT + ocol0 + n * 16] = acc[m][n][r] + bb;
      }
    }
  }
}

// ---------- launch ----------
extern "C" void kernel_launch(void* const* d_in, const int* in_sizes, int n_in,
                              void* d_out, int out_size, void* d_ws, size_t ws_size,
                              hipStream_t stream) {
  const float* x = (const float*)d_in[0];
  const float* w = (const float*)d_in[1];
  const float* bias = (const float*)d_in[2];
  float* out = (float*)d_out;

  char* ws = (char*)d_ws;
  uint32* hist1 = (uint32*)ws;                       // 2048 bins @ 0
  uint32* hs1   = (uint32*)(ws + 8192);              // 1024 bins
  uint32* hs2   = (uint32*)(ws + 12288);             // 1024 bins
  uint32* cnt   = (uint32*)(ws + 16384);             // 1 word
  ushort_t* Xb  = (ushort_t*)(ws + 65536);
  ushort_t* Wb  = (ushort_t*)(ws + 65536 + (size_t)NW * 2);
  uint2*   cand = (uint2*)(ws + 65536 + (size_t)NW * 4);

  hipMemsetAsync(d_ws, 0, 16448, stream);

  k1_hist1<<<2048, 256, 0, stream>>>((const uint4*)w, hist1);
  k2_decide_convx<<<1536, 256, 0, stream>>>((const float4*)w, hist1, (uint4*)Wb, cand, cnt, hs1,
                                            (const float4*)x, (uint4*)Xb);
  s2_hist<<<256, 256, 0, stream>>>(cand, cnt, hist1, hs1, hs2);
  k5_fixup<<<256, 256, 0, stream>>>(cand, cnt, hist1, hs1, hs2, Wb);

  gemm_bt<<<256, 512, 131072, stream>>>(Xb, Wb, bias, out);
}